// Round 1
// baseline (906.992 us; speedup 1.0000x reference)
//
#include <hip/hip_runtime.h>

typedef __bf16 bf16x8 __attribute__((ext_vector_type(8)));
typedef float f32x4 __attribute__((ext_vector_type(4)));
typedef unsigned int u32x4 __attribute__((ext_vector_type(4)));
typedef unsigned short u16;
typedef unsigned long long u64;

__device__ __forceinline__ u16 f2bf(float f) {
  unsigned u = __builtin_bit_cast(unsigned, f);
  u += 0x7FFFu + ((u >> 16) & 1u);   // RNE
  return (u16)(u >> 16);
}
__device__ __forceinline__ float bflo(unsigned u) { return __builtin_bit_cast(float, u << 16); }
__device__ __forceinline__ float bfhi(unsigned u) { return __builtin_bit_cast(float, u & 0xFFFF0000u); }

// ---------------- cast x (fp32 -> bf16), vectorized ----------------
__global__ void cast_x_kernel(const float* __restrict__ in, u16* __restrict__ out, int n4) {
  int i = blockIdx.x * blockDim.x + threadIdx.x;
  if (i >= n4) return;
  f32x4 v = *(const f32x4*)(in + (size_t)i * 4);
  u64 pk = (u64)f2bf(v[0]) | ((u64)f2bf(v[1]) << 16) | ((u64)f2bf(v[2]) << 32) | ((u64)f2bf(v[3]) << 48);
  *(u64*)(out + (size_t)i * 4) = pk;
}

// ------------- transpose + cast: W[K][N] fp32 -> WT[N][K] bf16 -------------
__global__ void transpose_cast_kernel(const float* __restrict__ W, u16* __restrict__ WT, int K, int N) {
  __shared__ float tile[32][33];
  int c0 = blockIdx.x * 32, r0 = blockIdx.y * 32;
  int tx = threadIdx.x & 31, tg = threadIdx.x >> 5;  // tg in 0..7
#pragma unroll
  for (int i = 0; i < 4; ++i) {
    int r = tg + i * 8;
    tile[r][tx] = W[(size_t)(r0 + r) * N + c0 + tx];
  }
  __syncthreads();
#pragma unroll
  for (int i = 0; i < 4; ++i) {
    int r = tg + i * 8;
    WT[(size_t)(c0 + r) * K + r0 + tx] = f2bf(tile[tx][r]);
  }
}

// ---------------- QKV GEMM: [8192x768] x [768x2304] via MFMA bf16 ----------------
// A: xb bf16 [M x 768]; BT: WqkvT bf16 [2304 x 768]; scatter into Q/K/V [B,H,T,D] bf16
__global__ __launch_bounds__(256) void gemm_qkv_kernel(
    const u16* __restrict__ A, const u16* __restrict__ BT, const float* __restrict__ bias,
    u16* __restrict__ Qb, u16* __restrict__ Kb, u16* __restrict__ Vb) {
  constexpr int K = 768;
  __shared__ u16 Asm[64 * 32];
  __shared__ u16 Bsm[64 * 32];
  const int tid = threadIdx.x;
  const int m0 = blockIdx.y * 64, n0 = blockIdx.x * 64;
  const int wave = tid >> 6, lane = tid & 63;
  const int lrow = lane & 15, lquad = lane >> 4;
  const int sr = tid >> 2, sc = (tid & 3) * 8;
  const u16* Ap = A + (size_t)(m0 + sr) * K + sc;
  const u16* Bp = BT + (size_t)(n0 + sr) * K + sc;
  f32x4 acc[4] = {{0.f, 0.f, 0.f, 0.f}, {0.f, 0.f, 0.f, 0.f}, {0.f, 0.f, 0.f, 0.f}, {0.f, 0.f, 0.f, 0.f}};
  for (int k0 = 0; k0 < K; k0 += 32) {
    __syncthreads();
    *(u32x4*)&Asm[sr * 32 + sc] = *(const u32x4*)(Ap + k0);
    *(u32x4*)&Bsm[sr * 32 + sc] = *(const u32x4*)(Bp + k0);
    __syncthreads();
    const bf16x8 af = *(const bf16x8*)&Asm[(wave * 16 + lrow) * 32 + lquad * 8];
#pragma unroll
    for (int t = 0; t < 4; ++t) {
      const bf16x8 bfr = *(const bf16x8*)&Bsm[(t * 16 + lrow) * 32 + lquad * 8];
      acc[t] = __builtin_amdgcn_mfma_f32_16x16x32_bf16(af, bfr, acc[t], 0, 0, 0);
    }
  }
#pragma unroll
  for (int t = 0; t < 4; ++t) {
    const int n = n0 + t * 16 + lrow;
    const float bv = bias[n];
    const int sec = n / 768, c = n % 768, h = c >> 6, d = c & 63;
    u16* dst = (sec == 0) ? Qb : (sec == 1) ? Kb : Vb;
#pragma unroll
    for (int r = 0; r < 4; ++r) {
      const int m = m0 + wave * 16 + lquad * 4 + r;
      const int bb = m >> 11, trow = m & 2047;
      dst[(size_t)((bb * 12 + h) * 2048 + trow) * 64 + d] = f2bf(acc[t][r] + bv);
    }
  }
}

// ---------------- proj GEMM: [8192x768] x [768x768], fp32 out + bias ----------------
__global__ __launch_bounds__(256) void gemm_proj_kernel(
    const u16* __restrict__ A, const u16* __restrict__ BT, const float* __restrict__ bias,
    float* __restrict__ out) {
  constexpr int K = 768;
  __shared__ u16 Asm[64 * 32];
  __shared__ u16 Bsm[64 * 32];
  const int tid = threadIdx.x;
  const int m0 = blockIdx.y * 64, n0 = blockIdx.x * 64;
  const int wave = tid >> 6, lane = tid & 63;
  const int lrow = lane & 15, lquad = lane >> 4;
  const int sr = tid >> 2, sc = (tid & 3) * 8;
  const u16* Ap = A + (size_t)(m0 + sr) * K + sc;
  const u16* Bp = BT + (size_t)(n0 + sr) * K + sc;
  f32x4 acc[4] = {{0.f, 0.f, 0.f, 0.f}, {0.f, 0.f, 0.f, 0.f}, {0.f, 0.f, 0.f, 0.f}, {0.f, 0.f, 0.f, 0.f}};
  for (int k0 = 0; k0 < K; k0 += 32) {
    __syncthreads();
    *(u32x4*)&Asm[sr * 32 + sc] = *(const u32x4*)(Ap + k0);
    *(u32x4*)&Bsm[sr * 32 + sc] = *(const u32x4*)(Bp + k0);
    __syncthreads();
    const bf16x8 af = *(const bf16x8*)&Asm[(wave * 16 + lrow) * 32 + lquad * 8];
#pragma unroll
    for (int t = 0; t < 4; ++t) {
      const bf16x8 bfr = *(const bf16x8*)&Bsm[(t * 16 + lrow) * 32 + lquad * 8];
      acc[t] = __builtin_amdgcn_mfma_f32_16x16x32_bf16(af, bfr, acc[t], 0, 0, 0);
    }
  }
#pragma unroll
  for (int t = 0; t < 4; ++t) {
    const int n = n0 + t * 16 + lrow;
    const float bv = bias[n];
#pragma unroll
    for (int r = 0; r < 4; ++r) {
      const int m = m0 + wave * 16 + lquad * 4 + r;
      out[(size_t)m * 768 + n] = acc[t][r] + bv;
    }
  }
}

// ---------------- causal flash attention, fp32 SIMT ----------------
// Q/K/V bf16 [BH=48][T=2048][D=64]; out Yb bf16 [B][T][C=768] (i.e. [B,T,H,D])
__global__ __launch_bounds__(256) void attn_kernel(
    const u16* __restrict__ Qg, const u16* __restrict__ Kg, const u16* __restrict__ Vg,
    u16* __restrict__ Yb) {
  constexpr int T = 2048, D = 64;
  __shared__ float Qs[64 * 64];   // [q][d], pre-scaled
  __shared__ float KPs[64 * 64];  // K^T [d][k] during S; P [q][k] during PV
  __shared__ float Vs[64 * 64];   // [k][d]
  const int qt = blockIdx.x, bh = blockIdx.y;
  const int q0 = qt * 64;
  const int bidx = bh / 12, hidx = bh % 12;
  const int tid = threadIdx.x;
  const int tx = tid & 15, ty = tid >> 4;  // 16x16 thread grid, each does 4x4
  const int sr = tid >> 2, sc = tid & 3;   // staging: row, chunk
  const u16* Qp = Qg + (size_t)(bh * T + q0) * D;
  const u16* Kp = Kg + (size_t)bh * T * D;
  const u16* Vp = Vg + (size_t)bh * T * D;
  const float scale = 0.125f;  // 1/sqrt(64)

  // stage Q once (scaled)
#pragma unroll
  for (int p = 0; p < 2; ++p) {
    const int c = sc + p * 4;
    u32x4 q4 = *(const u32x4*)(Qp + sr * D + c * 8);
    f32x4 lo = {bflo(q4[0]) * scale, bfhi(q4[0]) * scale, bflo(q4[1]) * scale, bfhi(q4[1]) * scale};
    f32x4 hi = {bflo(q4[2]) * scale, bfhi(q4[2]) * scale, bflo(q4[3]) * scale, bfhi(q4[3]) * scale};
    *(f32x4*)&Qs[sr * 64 + c * 8] = lo;
    *(f32x4*)&Qs[sr * 64 + c * 8 + 4] = hi;
  }

  float m_i[4], l_i[4], o[4][4];
#pragma unroll
  for (int i = 0; i < 4; ++i) {
    m_i[i] = -1e30f;
    l_i[i] = 0.f;
#pragma unroll
    for (int j = 0; j < 4; ++j) o[i][j] = 0.f;
  }

  const int nkt = qt + 1;  // causal: only tiles with k0 <= q0
  for (int kt = 0; kt < nkt; ++kt) {
    const int k0 = kt * 64;
    __syncthreads();  // prev PV done with KPs/Vs
    // stage K (transposed -> KPs[d][k]) and V (-> Vs[k][d])
#pragma unroll
    for (int p = 0; p < 2; ++p) {
      const int c = sc + p * 4;
      u32x4 k4 = *(const u32x4*)(Kp + (size_t)(k0 + sr) * D + c * 8);
      u32x4 v4 = *(const u32x4*)(Vp + (size_t)(k0 + sr) * D + c * 8);
      float kvv[8] = {bflo(k4[0]), bfhi(k4[0]), bflo(k4[1]), bfhi(k4[1]),
                      bflo(k4[2]), bfhi(k4[2]), bflo(k4[3]), bfhi(k4[3])};
#pragma unroll
      for (int e = 0; e < 8; ++e) KPs[(c * 8 + e) * 64 + sr] = kvv[e];
      f32x4 vlo = {bflo(v4[0]), bfhi(v4[0]), bflo(v4[1]), bfhi(v4[1])};
      f32x4 vhi = {bflo(v4[2]), bfhi(v4[2]), bflo(v4[3]), bfhi(v4[3])};
      *(f32x4*)&Vs[sr * 64 + c * 8] = vlo;
      *(f32x4*)&Vs[sr * 64 + c * 8 + 4] = vhi;
    }
    __syncthreads();
    // S[i][j] = sum_d Q[q0+ty*4+i][d] * K[k0+tx*4+j][d]   (Q pre-scaled)
    float s[4][4] = {};
#pragma unroll 4
    for (int d = 0; d < 64; d += 4) {
      f32x4 qv[4], kv[4];
#pragma unroll
      for (int i = 0; i < 4; ++i) qv[i] = *(const f32x4*)&Qs[(ty * 4 + i) * 64 + d];
#pragma unroll
      for (int r = 0; r < 4; ++r) kv[r] = *(const f32x4*)&KPs[(d + r) * 64 + tx * 4];
#pragma unroll
      for (int r = 0; r < 4; ++r)
#pragma unroll
        for (int i = 0; i < 4; ++i)
#pragma unroll
          for (int j = 0; j < 4; ++j) s[i][j] += qv[i][r] * kv[r][j];
    }
    __syncthreads();  // all waves done reading KPs (about to become P)
    if (kt == qt) {   // causal mask on the diagonal tile
#pragma unroll
      for (int i = 0; i < 4; ++i)
#pragma unroll
        for (int j = 0; j < 4; ++j)
          if (k0 + tx * 4 + j > q0 + ty * 4 + i) s[i][j] = -1e30f;
    }
    // online softmax (rows owned by fixed ty across the 16 tx lanes)
#pragma unroll
    for (int i = 0; i < 4; ++i) {
      float lm = fmaxf(fmaxf(s[i][0], s[i][1]), fmaxf(s[i][2], s[i][3]));
      for (int off = 1; off < 16; off <<= 1) lm = fmaxf(lm, __shfl_xor(lm, off));
      const float nm = fmaxf(m_i[i], lm);
      const float alpha = __expf(m_i[i] - nm);
      m_i[i] = nm;
      float ls = 0.f;
#pragma unroll
      for (int j = 0; j < 4; ++j) {
        s[i][j] = __expf(s[i][j] - nm);
        ls += s[i][j];
      }
      for (int off = 1; off < 16; off <<= 1) ls += __shfl_xor(ls, off);
      l_i[i] = l_i[i] * alpha + ls;
#pragma unroll
      for (int j = 0; j < 4; ++j) o[i][j] *= alpha;
      f32x4 pr = {s[i][0], s[i][1], s[i][2], s[i][3]};
      *(f32x4*)&KPs[(ty * 4 + i) * 64 + tx * 4] = pr;
    }
    __syncthreads();  // P visible
    // O[i][j] += sum_kk P[ty*4+i][kk] * V[kk][tx*4+j]
#pragma unroll 4
    for (int kk = 0; kk < 64; kk += 4) {
      f32x4 pv[4], vv[4];
#pragma unroll
      for (int i = 0; i < 4; ++i) pv[i] = *(const f32x4*)&KPs[(ty * 4 + i) * 64 + kk];
#pragma unroll
      for (int r = 0; r < 4; ++r) vv[r] = *(const f32x4*)&Vs[(kk + r) * 64 + tx * 4];
#pragma unroll
      for (int r = 0; r < 4; ++r)
#pragma unroll
        for (int i = 0; i < 4; ++i)
#pragma unroll
          for (int j = 0; j < 4; ++j) o[i][j] += pv[i][r] * vv[r][j];
    }
  }
  // epilogue: O /= l, write bf16 into [B,T,H,D] (= [B,T,C])
#pragma unroll
  for (int i = 0; i < 4; ++i) {
    const float inv = 1.f / l_i[i];
    const int q = q0 + ty * 4 + i;
    u64 pk = 0;
#pragma unroll
    for (int j = 0; j < 4; ++j) pk |= (u64)f2bf(o[i][j] * inv) << (16 * j);
    *(u64*)(Yb + (size_t)(bidx * T + q) * 768 + hidx * 64 + tx * 4) = pk;
  }
}

extern "C" void kernel_launch(void* const* d_in, const int* in_sizes, int n_in,
                              void* d_out, int out_size, void* d_ws, size_t ws_size,
                              hipStream_t stream) {
  const float* x = (const float*)d_in[0];
  const float* W_qkv = (const float*)d_in[1];
  const float* b_qkv = (const float*)d_in[2];
  const float* W_proj = (const float*)d_in[3];
  const float* b_proj = (const float*)d_in[4];
  float* out = (float*)d_out;

  constexpr size_t MC = (size_t)8192 * 768;  // 6291456
  u16* xb = (u16*)d_ws;
  u16* Qb = xb + MC;
  u16* Kb = Qb + MC;
  u16* Vb = Kb + MC;
  u16* Yb = Vb + MC;
  u16* WqkvT = Yb + MC;            // 2304*768
  u16* WprojT = WqkvT + (size_t)2304 * 768;  // 768*768; total ~67.6 MB

  cast_x_kernel<<<6291456 / (4 * 256), 256, 0, stream>>>(x, xb, 6291456 / 4);
  transpose_cast_kernel<<<dim3(2304 / 32, 768 / 32), 256, 0, stream>>>(W_qkv, WqkvT, 768, 2304);
  transpose_cast_kernel<<<dim3(768 / 32, 768 / 32), 256, 0, stream>>>(W_proj, WprojT, 768, 768);
  gemm_qkv_kernel<<<dim3(36, 128), 256, 0, stream>>>(xb, WqkvT, b_qkv, Qb, Kb, Vb);
  attn_kernel<<<dim3(32, 48), 256, 0, stream>>>(Qb, Kb, Vb, Yb);
  gemm_proj_kernel<<<dim3(12, 128), 256, 0, stream>>>(Yb, WprojT, b_proj, out);
}

// Round 2
// 376.379 us; speedup vs baseline: 2.4098x; 2.4098x over previous
//
#include <hip/hip_runtime.h>

typedef __bf16 bf16x8 __attribute__((ext_vector_type(8)));
typedef float f32x4 __attribute__((ext_vector_type(4)));
typedef unsigned int u32x4 __attribute__((ext_vector_type(4)));
typedef unsigned short u16;
typedef unsigned long long u64;

__device__ __forceinline__ u16 f2bf(float f) {
  unsigned u = __builtin_bit_cast(unsigned, f);
  u += 0x7FFFu + ((u >> 16) & 1u);   // RNE
  return (u16)(u >> 16);
}
__device__ __forceinline__ float bflo(unsigned u) { return __builtin_bit_cast(float, u << 16); }

// ---------------- cast x (fp32 -> bf16), vectorized ----------------
__global__ void cast_x_kernel(const float* __restrict__ in, u16* __restrict__ out, int n4) {
  int i = blockIdx.x * blockDim.x + threadIdx.x;
  if (i >= n4) return;
  f32x4 v = *(const f32x4*)(in + (size_t)i * 4);
  u64 pk = (u64)f2bf(v[0]) | ((u64)f2bf(v[1]) << 16) | ((u64)f2bf(v[2]) << 32) | ((u64)f2bf(v[3]) << 48);
  *(u64*)(out + (size_t)i * 4) = pk;
}

// ------------- transpose + cast: W[K][N] fp32 -> WT[N][K] bf16 -------------
__global__ void transpose_cast_kernel(const float* __restrict__ W, u16* __restrict__ WT, int K, int N) {
  __shared__ float tile[32][33];
  int c0 = blockIdx.x * 32, r0 = blockIdx.y * 32;
  int tx = threadIdx.x & 31, tg = threadIdx.x >> 5;  // tg in 0..7
#pragma unroll
  for (int i = 0; i < 4; ++i) {
    int r = tg + i * 8;
    tile[r][tx] = W[(size_t)(r0 + r) * N + c0 + tx];
  }
  __syncthreads();
#pragma unroll
  for (int i = 0; i < 4; ++i) {
    int r = tg + i * 8;
    WT[(size_t)(c0 + r) * K + r0 + tx] = f2bf(tile[tx][r]);
  }
}

// ---------------- QKV GEMM: [8192x768] x [768x2304] via MFMA bf16 ----------------
// Q pre-scaled by 0.125 (attention scale). V written TRANSPOSED: Vt[bh][d][t].
__global__ __launch_bounds__(256) void gemm_qkv_kernel(
    const u16* __restrict__ A, const u16* __restrict__ BT, const float* __restrict__ bias,
    u16* __restrict__ Qb, u16* __restrict__ Kb, u16* __restrict__ Vt) {
  constexpr int K = 768;
  __shared__ u16 Asm[64 * 32];
  __shared__ u16 Bsm[64 * 32];
  const int tid = threadIdx.x;
  const int m0 = blockIdx.y * 64, n0 = blockIdx.x * 64;
  const int wave = tid >> 6, lane = tid & 63;
  const int lrow = lane & 15, lquad = lane >> 4;
  const int sr = tid >> 2, sc = (tid & 3) * 8;
  const u16* Ap = A + (size_t)(m0 + sr) * K + sc;
  const u16* Bp = BT + (size_t)(n0 + sr) * K + sc;
  f32x4 acc[4] = {{0.f, 0.f, 0.f, 0.f}, {0.f, 0.f, 0.f, 0.f}, {0.f, 0.f, 0.f, 0.f}, {0.f, 0.f, 0.f, 0.f}};
  for (int k0 = 0; k0 < K; k0 += 32) {
    __syncthreads();
    *(u32x4*)&Asm[sr * 32 + sc] = *(const u32x4*)(Ap + k0);
    *(u32x4*)&Bsm[sr * 32 + sc] = *(const u32x4*)(Bp + k0);
    __syncthreads();
    const bf16x8 af = *(const bf16x8*)&Asm[(wave * 16 + lrow) * 32 + lquad * 8];
#pragma unroll
    for (int t = 0; t < 4; ++t) {
      const bf16x8 bfr = *(const bf16x8*)&Bsm[(t * 16 + lrow) * 32 + lquad * 8];
      acc[t] = __builtin_amdgcn_mfma_f32_16x16x32_bf16(af, bfr, acc[t], 0, 0, 0);
    }
  }
#pragma unroll
  for (int t = 0; t < 4; ++t) {
    const int n = n0 + t * 16 + lrow;
    const float bv = bias[n];
    const int sec = n / 768, c = n % 768, h = c >> 6, d = c & 63;
    const int mB = m0 + wave * 16 + lquad * 4;
    const int bb = mB >> 11, trow = mB & 2047;
    if (sec == 2) {
      // V transposed: Vt[(bh*64 + d)*2048 + t]; 4 consecutive trow -> one u64
      u64 pk = 0;
#pragma unroll
      for (int r = 0; r < 4; ++r) pk |= (u64)f2bf(acc[t][r] + bv) << (16 * r);
      *(u64*)(Vt + (size_t)((bb * 12 + h) * 64 + d) * 2048 + trow) = pk;
    } else {
      u16* dst = (sec == 0) ? Qb : Kb;
      const float scl = (sec == 0) ? 0.125f : 1.0f;  // fold attention scale into Q
#pragma unroll
      for (int r = 0; r < 4; ++r)
        dst[(size_t)((bb * 12 + h) * 2048 + trow + r) * 64 + d] = f2bf((acc[t][r] + bv) * scl);
    }
  }
}

// ---------------- proj GEMM: [8192x768] x [768x768], fp32 out + bias ----------------
__global__ __launch_bounds__(256) void gemm_proj_kernel(
    const u16* __restrict__ A, const u16* __restrict__ BT, const float* __restrict__ bias,
    float* __restrict__ out) {
  constexpr int K = 768;
  __shared__ u16 Asm[64 * 32];
  __shared__ u16 Bsm[64 * 32];
  const int tid = threadIdx.x;
  const int m0 = blockIdx.y * 64, n0 = blockIdx.x * 64;
  const int wave = tid >> 6, lane = tid & 63;
  const int lrow = lane & 15, lquad = lane >> 4;
  const int sr = tid >> 2, sc = (tid & 3) * 8;
  const u16* Ap = A + (size_t)(m0 + sr) * K + sc;
  const u16* Bp = BT + (size_t)(n0 + sr) * K + sc;
  f32x4 acc[4] = {{0.f, 0.f, 0.f, 0.f}, {0.f, 0.f, 0.f, 0.f}, {0.f, 0.f, 0.f, 0.f}, {0.f, 0.f, 0.f, 0.f}};
  for (int k0 = 0; k0 < K; k0 += 32) {
    __syncthreads();
    *(u32x4*)&Asm[sr * 32 + sc] = *(const u32x4*)(Ap + k0);
    *(u32x4*)&Bsm[sr * 32 + sc] = *(const u32x4*)(Bp + k0);
    __syncthreads();
    const bf16x8 af = *(const bf16x8*)&Asm[(wave * 16 + lrow) * 32 + lquad * 8];
#pragma unroll
    for (int t = 0; t < 4; ++t) {
      const bf16x8 bfr = *(const bf16x8*)&Bsm[(t * 16 + lrow) * 32 + lquad * 8];
      acc[t] = __builtin_amdgcn_mfma_f32_16x16x32_bf16(af, bfr, acc[t], 0, 0, 0);
    }
  }
#pragma unroll
  for (int t = 0; t < 4; ++t) {
    const int n = n0 + t * 16 + lrow;
    const float bv = bias[n];
#pragma unroll
    for (int r = 0; r < 4; ++r) {
      const int m = m0 + wave * 16 + lquad * 4 + r;
      out[(size_t)m * 768 + n] = acc[t][r] + bv;
    }
  }
}

// ---------------- causal flash attention, MFMA bf16 ----------------
// Q (pre-scaled) [bh][t][d]; K [bh][t][d]; Vt TRANSPOSED [bh][d][t]; out Yb bf16 [B][T][C]
__global__ __launch_bounds__(256) void attn_kernel(
    const u16* __restrict__ Qg, const u16* __restrict__ Kg, const u16* __restrict__ Vtg,
    u16* __restrict__ Yb) {
  constexpr int T = 2048, D = 64;
  constexpr int LDP = 72;  // padded LDS row stride (u16): breaks pow2 bank aliasing, 144B = 16B-aligned
  __shared__ u16 Ks[64 * LDP];    // K tile  [k][d]
  __shared__ u16 VTs[64 * LDP];   // V^T tile [d][k]
  __shared__ u16 Ps[4 * 16 * LDP];// P per-wave [16 q][64 k] bf16
  const int qt = blockIdx.x, bh = blockIdx.y;
  const int q0 = qt * 64;
  const int bidx = bh / 12, hidx = bh % 12;
  const int tid = threadIdx.x;
  const int w = tid >> 6, lane = tid & 63;
  const int l15 = lane & 15, quad = lane >> 4;
  const int srow = tid >> 2, scol = (tid & 3) * 8;  // staging: 64 rows x 2 chunks of 8 u16
  const u16* Kp = Kg + (size_t)bh * T * D;
  const u16* VTp = Vtg + (size_t)bh * D * T;
  u16* pw = &Ps[w * 16 * LDP];

  // Q fragments in registers (A-layout): lane holds Q[q0+w*16+l15][quad*8+j], and +32
  const u16* qrow = Qg + ((size_t)bh * T + q0 + w * 16 + l15) * D;
  const bf16x8 qf0 = *(const bf16x8*)(qrow + quad * 8);
  const bf16x8 qf1 = *(const bf16x8*)(qrow + 32 + quad * 8);

  f32x4 o_acc[4] = {{0.f, 0.f, 0.f, 0.f}, {0.f, 0.f, 0.f, 0.f}, {0.f, 0.f, 0.f, 0.f}, {0.f, 0.f, 0.f, 0.f}};
  float m_i[4] = {-1e30f, -1e30f, -1e30f, -1e30f};
  float l_i[4] = {0.f, 0.f, 0.f, 0.f};

  for (int kt = 0; kt <= qt; ++kt) {
    const int k0 = kt * 64;
    __syncthreads();  // prev iteration's MFMA reads of Ks/VTs complete
#pragma unroll
    for (int p = 0; p < 2; ++p) {
      const int c = scol + p * 32;
      *(u32x4*)&Ks[srow * LDP + c] = *(const u32x4*)(Kp + (size_t)(k0 + srow) * D + c);
      *(u32x4*)&VTs[srow * LDP + c] = *(const u32x4*)(VTp + (size_t)srow * T + k0 + c);
    }
    __syncthreads();

    // S = Q * K^T  (Q pre-scaled by 1/8). C-layout: row=quad*4+r, col=t*16+l15
    f32x4 s_acc[4] = {{0.f, 0.f, 0.f, 0.f}, {0.f, 0.f, 0.f, 0.f}, {0.f, 0.f, 0.f, 0.f}, {0.f, 0.f, 0.f, 0.f}};
#pragma unroll
    for (int t = 0; t < 4; ++t) {
      const bf16x8 kf0 = *(const bf16x8*)&Ks[(t * 16 + l15) * LDP + quad * 8];
      const bf16x8 kf1 = *(const bf16x8*)&Ks[(t * 16 + l15) * LDP + 32 + quad * 8];
      s_acc[t] = __builtin_amdgcn_mfma_f32_16x16x32_bf16(qf0, kf0, s_acc[t], 0, 0, 0);
      s_acc[t] = __builtin_amdgcn_mfma_f32_16x16x32_bf16(qf1, kf1, s_acc[t], 0, 0, 0);
    }
    if (kt == qt) {  // causal mask, diagonal tile
#pragma unroll
      for (int t = 0; t < 4; ++t)
#pragma unroll
        for (int r = 0; r < 4; ++r)
          if (k0 + t * 16 + l15 > q0 + w * 16 + quad * 4 + r) s_acc[t][r] = -1e30f;
    }
    // online softmax: lane owns rows quad*4+r across 16 lanes (cols t*16+l15)
#pragma unroll
    for (int r = 0; r < 4; ++r) {
      float lm = fmaxf(fmaxf(s_acc[0][r], s_acc[1][r]), fmaxf(s_acc[2][r], s_acc[3][r]));
#pragma unroll
      for (int off = 1; off < 16; off <<= 1) lm = fmaxf(lm, __shfl_xor(lm, off));
      const float nm = fmaxf(m_i[r], lm);
      const float alpha = __expf(m_i[r] - nm);
      m_i[r] = nm;
      float ls = 0.f;
#pragma unroll
      for (int t = 0; t < 4; ++t) {
        const u16 pb = f2bf(__expf(s_acc[t][r] - nm));
        ls += bflo(pb);  // sum the bf16-rounded value: consistent with PV numerator
        pw[(quad * 4 + r) * LDP + t * 16 + l15] = pb;
      }
#pragma unroll
      for (int off = 1; off < 16; off <<= 1) ls += __shfl_xor(ls, off);
      l_i[r] = l_i[r] * alpha + ls;
#pragma unroll
      for (int t = 0; t < 4; ++t) o_acc[t][r] *= alpha;
    }
    // O += P * V  (P from own wave's LDS region -> A-frags; V^T rows -> B-frags)
    const bf16x8 pf0 = *(const bf16x8*)&pw[l15 * LDP + quad * 8];
    const bf16x8 pf1 = *(const bf16x8*)&pw[l15 * LDP + 32 + quad * 8];
#pragma unroll
    for (int t = 0; t < 4; ++t) {
      const bf16x8 vf0 = *(const bf16x8*)&VTs[(t * 16 + l15) * LDP + quad * 8];
      const bf16x8 vf1 = *(const bf16x8*)&VTs[(t * 16 + l15) * LDP + 32 + quad * 8];
      o_acc[t] = __builtin_amdgcn_mfma_f32_16x16x32_bf16(pf0, vf0, o_acc[t], 0, 0, 0);
      o_acc[t] = __builtin_amdgcn_mfma_f32_16x16x32_bf16(pf1, vf1, o_acc[t], 0, 0, 0);
    }
  }
  // epilogue: O /= l, bf16, write [B,T,H,D]
#pragma unroll
  for (int r = 0; r < 4; ++r) {
    const float inv = 1.f / l_i[r];
    const int q = q0 + w * 16 + quad * 4 + r;
    u16* yrow = Yb + ((size_t)bidx * T + q) * 768 + hidx * 64;
#pragma unroll
    for (int t = 0; t < 4; ++t) yrow[t * 16 + l15] = f2bf(o_acc[t][r] * inv);
  }
}

extern "C" void kernel_launch(void* const* d_in, const int* in_sizes, int n_in,
                              void* d_out, int out_size, void* d_ws, size_t ws_size,
                              hipStream_t stream) {
  const float* x = (const float*)d_in[0];
  const float* W_qkv = (const float*)d_in[1];
  const float* b_qkv = (const float*)d_in[2];
  const float* W_proj = (const float*)d_in[3];
  const float* b_proj = (const float*)d_in[4];
  float* out = (float*)d_out;

  constexpr size_t MC = (size_t)8192 * 768;  // 6291456
  u16* xb = (u16*)d_ws;
  u16* Qb = xb + MC;
  u16* Kb = Qb + MC;
  u16* Vt = Kb + MC;   // transposed V: [bh][d][t]
  u16* Yb = Vt + MC;
  u16* WqkvT = Yb + MC;                      // 2304*768
  u16* WprojT = WqkvT + (size_t)2304 * 768;  // 768*768; total ~67.6 MB

  cast_x_kernel<<<6291456 / (4 * 256), 256, 0, stream>>>(x, xb, 6291456 / 4);
  transpose_cast_kernel<<<dim3(2304 / 32, 768 / 32), 256, 0, stream>>>(W_qkv, WqkvT, 768, 2304);
  transpose_cast_kernel<<<dim3(768 / 32, 768 / 32), 256, 0, stream>>>(W_proj, WprojT, 768, 768);
  gemm_qkv_kernel<<<dim3(36, 128), 256, 0, stream>>>(xb, WqkvT, b_qkv, Qb, Kb, Vt);
  attn_kernel<<<dim3(32, 48), 256, 0, stream>>>(Qb, Kb, Vt, Yb);
  gemm_proj_kernel<<<dim3(12, 128), 256, 0, stream>>>(Yb, WprojT, b_proj, out);
}

// Round 3
// 309.333 us; speedup vs baseline: 2.9321x; 1.2167x over previous
//
#include <hip/hip_runtime.h>

typedef __bf16 bf16x8 __attribute__((ext_vector_type(8)));
typedef float f32x4 __attribute__((ext_vector_type(4)));
typedef unsigned int u32x4 __attribute__((ext_vector_type(4)));
typedef unsigned short u16;
typedef unsigned long long u64;

__device__ __forceinline__ u16 f2bf(float f) {
  unsigned u = __builtin_bit_cast(unsigned, f);
  u += 0x7FFFu + ((u >> 16) & 1u);   // RNE
  return (u16)(u >> 16);
}
__device__ __forceinline__ float bflo(unsigned u) { return __builtin_bit_cast(float, u << 16); }

// async global->LDS direct copy, 16B per lane. LDS dest = wave-uniform base + lane*16.
__device__ __forceinline__ void gll16(const u16* g, u16* l) {
  __builtin_amdgcn_global_load_lds(
      (const __attribute__((address_space(1))) unsigned int*)g,
      (__attribute__((address_space(3))) unsigned int*)l, 16, 0, 0);
}

// ---------------- cast x (fp32 -> bf16), vectorized ----------------
__global__ void cast_x_kernel(const float* __restrict__ in, u16* __restrict__ out, int n4) {
  int i = blockIdx.x * blockDim.x + threadIdx.x;
  if (i >= n4) return;
  f32x4 v = *(const f32x4*)(in + (size_t)i * 4);
  u64 pk = (u64)f2bf(v[0]) | ((u64)f2bf(v[1]) << 16) | ((u64)f2bf(v[2]) << 32) | ((u64)f2bf(v[3]) << 48);
  *(u64*)(out + (size_t)i * 4) = pk;
}

// ------------- transpose + cast: W[K][N] fp32 -> WT[N][K] bf16 -------------
__global__ void transpose_cast_kernel(const float* __restrict__ W, u16* __restrict__ WT, int K, int N) {
  __shared__ float tile[32][33];
  int c0 = blockIdx.x * 32, r0 = blockIdx.y * 32;
  int tx = threadIdx.x & 31, tg = threadIdx.x >> 5;
#pragma unroll
  for (int i = 0; i < 4; ++i) {
    int r = tg + i * 8;
    tile[r][tx] = W[(size_t)(r0 + r) * N + c0 + tx];
  }
  __syncthreads();
#pragma unroll
  for (int i = 0; i < 4; ++i) {
    int r = tg + i * 8;
    WT[(size_t)(c0 + r) * K + r0 + tx] = f2bf(tile[tx][r]);
  }
}

// ======== shared 128x128 MFMA mainloop (m97-style: BK=32, global_load_lds) ========
// Computes acc[i][j] (4x4 of 16x16) for this thread's wave quadrant.
// A [M x 768] bf16 row-major; BT [N x 768] bf16 row-major (B transposed).
#define GEMM128_MAINLOOP(A, BT, m0, n0)                                                     \
  constexpr int K = 768;                                                                    \
  __shared__ u16 Asm[128 * 32];                                                             \
  __shared__ u16 Bsm[128 * 32];                                                             \
  const int tid = threadIdx.x;                                                              \
  const int w = tid >> 6, lane = tid & 63;                                                  \
  const int l15 = lane & 15, quad = lane >> 4;                                              \
  const int srow = tid >> 2, scol = (tid & 3) * 8;                                          \
  const u16* Ag0 = (A) + (size_t)((m0) + srow) * K + scol;                                  \
  const u16* Ag1 = (A) + (size_t)((m0) + 64 + srow) * K + scol;                             \
  const u16* Bg0 = (BT) + (size_t)((n0) + srow) * K + scol;                                 \
  const u16* Bg1 = (BT) + (size_t)((n0) + 64 + srow) * K + scol;                            \
  u16* Al0 = &Asm[(w * 64) * 8];                                                            \
  u16* Al1 = &Asm[(256 + w * 64) * 8];                                                      \
  u16* Bl0 = &Bsm[(w * 64) * 8];                                                            \
  u16* Bl1 = &Bsm[(256 + w * 64) * 8];                                                      \
  const int mw = (w >> 1) * 64, nw = (w & 1) * 64;                                          \
  f32x4 acc[4][4];                                                                          \
  _Pragma("unroll") for (int i = 0; i < 4; ++i) _Pragma("unroll") for (int j = 0; j < 4;    \
                                                                       ++j) acc[i][j] = {   \
      0.f, 0.f, 0.f, 0.f};                                                                  \
  for (int k0 = 0; k0 < K; k0 += 32) {                                                      \
    __syncthreads();                                                                        \
    gll16(Ag0 + k0, Al0);                                                                   \
    gll16(Ag1 + k0, Al1);                                                                   \
    gll16(Bg0 + k0, Bl0);                                                                   \
    gll16(Bg1 + k0, Bl1);                                                                   \
    __syncthreads();                                                                        \
    bf16x8 af[4], bfj[4];                                                                   \
    _Pragma("unroll") for (int i = 0; i < 4; ++i) af[i] =                                   \
        *(const bf16x8*)&Asm[(mw + i * 16 + l15) * 32 + quad * 8];                          \
    _Pragma("unroll") for (int j = 0; j < 4; ++j) bfj[j] =                                  \
        *(const bf16x8*)&Bsm[(nw + j * 16 + l15) * 32 + quad * 8];                          \
    _Pragma("unroll") for (int i = 0; i < 4; ++i) _Pragma("unroll") for (int j = 0; j < 4;  \
                                                                         ++j) acc[i][j] =  \
        __builtin_amdgcn_mfma_f32_16x16x32_bf16(af[i], bfj[j], acc[i][j], 0, 0, 0);         \
  }

// ---------------- QKV GEMM: [8192x768] x [768x2304] ----------------
// Q pre-scaled by 0.125. V written TRANSPOSED: Vt[bh][d][t].
__global__ __launch_bounds__(256) void gemm_qkv_kernel(
    const u16* __restrict__ A, const u16* __restrict__ BT, const float* __restrict__ bias,
    u16* __restrict__ Qb, u16* __restrict__ Kb, u16* __restrict__ Vt) {
  const int m0 = blockIdx.y * 128, n0 = blockIdx.x * 128;
  GEMM128_MAINLOOP(A, BT, m0, n0)
  const int sec = blockIdx.x / 6;           // 0:Q 1:K 2:V (uniform per block; 768%128==0)
  const int nbase = n0 - sec * 768;
#pragma unroll
  for (int j = 0; j < 4; ++j) {
    const int nloc = nbase + nw + j * 16 + l15;
    const float bv = bias[sec * 768 + nloc];
    const int h = nloc >> 6, d = nloc & 63;
#pragma unroll
    for (int i = 0; i < 4; ++i) {
      const int m = m0 + mw + i * 16 + quad * 4;
      const int bb = m >> 11, trow = m & 2047;
      if (sec == 2) {
        u64 pk = 0;
#pragma unroll
        for (int r = 0; r < 4; ++r) pk |= (u64)f2bf(acc[i][j][r] + bv) << (16 * r);
        *(u64*)(Vt + (size_t)((bb * 12 + h) * 64 + d) * 2048 + trow) = pk;
      } else {
        u16* dst = (sec == 0) ? Qb : Kb;
        const float scl = (sec == 0) ? 0.125f : 1.0f;
#pragma unroll
        for (int r = 0; r < 4; ++r)
          dst[(size_t)((bb * 12 + h) * 2048 + trow + r) * 64 + d] = f2bf((acc[i][j][r] + bv) * scl);
      }
    }
  }
}

// ---------------- proj GEMM: [8192x768] x [768x768], fp32 out + bias ----------------
__global__ __launch_bounds__(256) void gemm_proj_kernel(
    const u16* __restrict__ A, const u16* __restrict__ BT, const float* __restrict__ bias,
    float* __restrict__ out) {
  const int m0 = blockIdx.y * 128, n0 = blockIdx.x * 128;
  GEMM128_MAINLOOP(A, BT, m0, n0)
#pragma unroll
  for (int j = 0; j < 4; ++j) {
    const int n = n0 + nw + j * 16 + l15;
    const float bv = bias[n];
#pragma unroll
    for (int i = 0; i < 4; ++i) {
      const int m = m0 + mw + i * 16 + quad * 4;
#pragma unroll
      for (int r = 0; r < 4; ++r) out[(size_t)(m + r) * 768 + n] = acc[i][j][r] + bv;
    }
  }
}

// ---------------- causal flash attention, MFMA bf16, transposed-S softmax ----------------
// Q (pre-scaled) [bh][t][d]; K [bh][t][d]; Vt TRANSPOSED [bh][d][t]; out Yb bf16 [B][T][C]
__global__ __launch_bounds__(256) void attn_kernel(
    const u16* __restrict__ Qg, const u16* __restrict__ Kg, const u16* __restrict__ Vtg,
    u16* __restrict__ Yb) {
  constexpr int T = 2048, D = 64;
  constexpr int LDP = 72;  // padded LDS stride (u16)
  __shared__ u16 Ks[64 * LDP];     // K tile  [k][d]
  __shared__ u16 VTs[64 * LDP];    // V^T tile [d][k]
  __shared__ u16 Ps[4 * 16 * LDP]; // P per-wave [16 q][64 k]
  const int qt = 31 - blockIdx.x;  // descending work: LPT-style packing of the triangle
  const int bh = blockIdx.y;
  const int q0 = qt * 64;
  const int bidx = bh / 12, hidx = bh % 12;
  const int tid = threadIdx.x;
  const int w = tid >> 6, lane = tid & 63;
  const int l15 = lane & 15, quad = lane >> 4;
  const int srow = tid >> 2, scol = (tid & 3) * 8;
  const u16* Kp = Kg + (size_t)bh * T * D;
  const u16* VTp = Vtg + (size_t)bh * D * T;
  u16* pw = &Ps[w * 16 * LDP];

  // Q fragments (B-operand for S^T = K·Q^T): lane holds Q[q0+w*16+l15][quad*8+j]
  const u16* qrow = Qg + ((size_t)bh * T + q0 + w * 16 + l15) * D;
  const bf16x8 qf0 = *(const bf16x8*)(qrow + quad * 8);
  const bf16x8 qf1 = *(const bf16x8*)(qrow + 32 + quad * 8);
  const int qq = q0 + w * 16 + l15;  // this lane's q (for mask + softmax)

  f32x4 o_acc[4] = {{0.f, 0.f, 0.f, 0.f}, {0.f, 0.f, 0.f, 0.f}, {0.f, 0.f, 0.f, 0.f}, {0.f, 0.f, 0.f, 0.f}};
  float m_i = -1e30f, l_i = 0.f;

  for (int kt = 0; kt <= qt; ++kt) {
    const int k0 = kt * 64;
    __syncthreads();
#pragma unroll
    for (int p = 0; p < 2; ++p) {
      const int c = scol + p * 32;
      *(u32x4*)&Ks[srow * LDP + c] = *(const u32x4*)(Kp + (size_t)(k0 + srow) * D + c);
      *(u32x4*)&VTs[srow * LDP + c] = *(const u32x4*)(VTp + (size_t)srow * T + k0 + c);
    }
    __syncthreads();

    // S^T = K · Q^T : C-layout row = k_local = quad*4+r (+16t), col = q = l15
    f32x4 s_acc[4] = {{0.f, 0.f, 0.f, 0.f}, {0.f, 0.f, 0.f, 0.f}, {0.f, 0.f, 0.f, 0.f}, {0.f, 0.f, 0.f, 0.f}};
#pragma unroll
    for (int t = 0; t < 4; ++t) {
      const bf16x8 kf0 = *(const bf16x8*)&Ks[(t * 16 + l15) * LDP + quad * 8];
      const bf16x8 kf1 = *(const bf16x8*)&Ks[(t * 16 + l15) * LDP + 32 + quad * 8];
      s_acc[t] = __builtin_amdgcn_mfma_f32_16x16x32_bf16(kf0, qf0, s_acc[t], 0, 0, 0);
      s_acc[t] = __builtin_amdgcn_mfma_f32_16x16x32_bf16(kf1, qf1, s_acc[t], 0, 0, 0);
    }
    if (kt == qt) {  // causal mask on the diagonal tile
#pragma unroll
      for (int t = 0; t < 4; ++t)
#pragma unroll
        for (int r = 0; r < 4; ++r)
          if (k0 + t * 16 + quad * 4 + r > qq) s_acc[t][r] = -1e30f;
    }
    // per-lane softmax for q = qq: 16 values within lane + cross-quad (xor16, xor32)
    float lm = -1e30f;
#pragma unroll
    for (int t = 0; t < 4; ++t)
#pragma unroll
      for (int r = 0; r < 4; ++r) lm = fmaxf(lm, s_acc[t][r]);
    lm = fmaxf(lm, __shfl_xor(lm, 16));
    lm = fmaxf(lm, __shfl_xor(lm, 32));
    const float nm = fmaxf(m_i, lm);
    const float alpha = __expf(m_i - nm);
    m_i = nm;
    float ls = 0.f;
#pragma unroll
    for (int t = 0; t < 4; ++t) {
      u64 pk = 0;
#pragma unroll
      for (int r = 0; r < 4; ++r) {
        const u16 pb = f2bf(__expf(s_acc[t][r] - nm));
        ls += bflo(pb);  // sum bf16-rounded values: consistent with PV numerator
        pk |= (u64)pb << (16 * r);
      }
      *(u64*)&pw[l15 * LDP + t * 16 + quad * 4] = pk;  // P[q_local=l15][k=16t+quad*4..+3]
    }
    ls += __shfl_xor(ls, 16);
    ls += __shfl_xor(ls, 32);
    l_i = l_i * alpha + ls;
    // redistribute alpha to O's C-layout rows (q_local = quad*4+r)
    float ar[4];
#pragma unroll
    for (int r = 0; r < 4; ++r) ar[r] = __shfl(alpha, (quad << 4) | (quad * 4 + r));
#pragma unroll
    for (int t = 0; t < 4; ++t)
#pragma unroll
      for (int r = 0; r < 4; ++r) o_acc[t][r] *= ar[r];
    // O += P · V^T  (P rows q_local from own wave's LDS; V^T rows as B-frags)
    const bf16x8 pf0 = *(const bf16x8*)&pw[l15 * LDP + quad * 8];
    const bf16x8 pf1 = *(const bf16x8*)&pw[l15 * LDP + 32 + quad * 8];
#pragma unroll
    for (int t = 0; t < 4; ++t) {
      const bf16x8 vf0 = *(const bf16x8*)&VTs[(t * 16 + l15) * LDP + quad * 8];
      const bf16x8 vf1 = *(const bf16x8*)&VTs[(t * 16 + l15) * LDP + 32 + quad * 8];
      o_acc[t] = __builtin_amdgcn_mfma_f32_16x16x32_bf16(pf0, vf0, o_acc[t], 0, 0, 0);
      o_acc[t] = __builtin_amdgcn_mfma_f32_16x16x32_bf16(pf1, vf1, o_acc[t], 0, 0, 0);
    }
  }
  // epilogue: redistribute l to C-layout rows, normalize, write [B,T,H,D]
#pragma unroll
  for (int r = 0; r < 4; ++r) {
    const float lr = __shfl(l_i, (quad << 4) | (quad * 4 + r));
    const float inv = 1.f / lr;
    const int q = q0 + w * 16 + quad * 4 + r;
    u16* yrow = Yb + ((size_t)bidx * T + q) * 768 + hidx * 64;
#pragma unroll
    for (int t = 0; t < 4; ++t) yrow[t * 16 + l15] = f2bf(o_acc[t][r] * inv);
  }
}

extern "C" void kernel_launch(void* const* d_in, const int* in_sizes, int n_in,
                              void* d_out, int out_size, void* d_ws, size_t ws_size,
                              hipStream_t stream) {
  const float* x = (const float*)d_in[0];
  const float* W_qkv = (const float*)d_in[1];
  const float* b_qkv = (const float*)d_in[2];
  const float* W_proj = (const float*)d_in[3];
  const float* b_proj = (const float*)d_in[4];
  float* out = (float*)d_out;

  constexpr size_t MC = (size_t)8192 * 768;
  u16* xb = (u16*)d_ws;
  u16* Qb = xb + MC;
  u16* Kb = Qb + MC;
  u16* Vt = Kb + MC;   // transposed V: [bh][d][t]
  u16* Yb = Vt + MC;
  u16* WqkvT = Yb + MC;
  u16* WprojT = WqkvT + (size_t)2304 * 768;

  cast_x_kernel<<<6291456 / (4 * 256), 256, 0, stream>>>(x, xb, 6291456 / 4);
  transpose_cast_kernel<<<dim3(2304 / 32, 768 / 32), 256, 0, stream>>>(W_qkv, WqkvT, 768, 2304);
  transpose_cast_kernel<<<dim3(768 / 32, 768 / 32), 256, 0, stream>>>(W_proj, WprojT, 768, 768);
  gemm_qkv_kernel<<<dim3(18, 64), 256, 0, stream>>>(xb, WqkvT, b_qkv, Qb, Kb, Vt);
  attn_kernel<<<dim3(32, 48), 256, 0, stream>>>(Qb, Kb, Vt, Yb);
  gemm_proj_kernel<<<dim3(6, 64), 256, 0, stream>>>(Yb, WprojT, b_proj, out);
}

// Round 4
// 300.165 us; speedup vs baseline: 3.0216x; 1.0305x over previous
//
#include <hip/hip_runtime.h>

typedef __bf16 bf16x8 __attribute__((ext_vector_type(8)));
typedef float f32x4 __attribute__((ext_vector_type(4)));
typedef unsigned int u32x4 __attribute__((ext_vector_type(4)));
typedef unsigned short u16;
typedef unsigned long long u64;

__device__ __forceinline__ u16 f2bf(float f) {
  unsigned u = __builtin_bit_cast(unsigned, f);
  u += 0x7FFFu + ((u >> 16) & 1u);   // RNE
  return (u16)(u >> 16);
}
__device__ __forceinline__ float bflo(unsigned u) { return __builtin_bit_cast(float, u << 16); }

// async global->LDS direct copy, 16B per lane. LDS dest = wave-uniform base + lane*16.
__device__ __forceinline__ void gll16(const u16* g, u16* l) {
  __builtin_amdgcn_global_load_lds(
      (const __attribute__((address_space(1))) unsigned int*)g,
      (__attribute__((address_space(3))) unsigned int*)l, 16, 0, 0);
}

// ---------------- cast x (fp32 -> bf16), vectorized ----------------
__global__ void cast_x_kernel(const float* __restrict__ in, u16* __restrict__ out, int n4) {
  int i = blockIdx.x * blockDim.x + threadIdx.x;
  if (i >= n4) return;
  f32x4 v = *(const f32x4*)(in + (size_t)i * 4);
  u64 pk = (u64)f2bf(v[0]) | ((u64)f2bf(v[1]) << 16) | ((u64)f2bf(v[2]) << 32) | ((u64)f2bf(v[3]) << 48);
  *(u64*)(out + (size_t)i * 4) = pk;
}

// ------------- transpose + cast: W[K][N] fp32 -> WT[N][K] bf16 -------------
__global__ void transpose_cast_kernel(const float* __restrict__ W, u16* __restrict__ WT, int K, int N) {
  __shared__ float tile[32][33];
  int c0 = blockIdx.x * 32, r0 = blockIdx.y * 32;
  int tx = threadIdx.x & 31, tg = threadIdx.x >> 5;
#pragma unroll
  for (int i = 0; i < 4; ++i) {
    int r = tg + i * 8;
    tile[r][tx] = W[(size_t)(r0 + r) * N + c0 + tx];
  }
  __syncthreads();
#pragma unroll
  for (int i = 0; i < 4; ++i) {
    int r = tg + i * 8;
    WT[(size_t)(c0 + r) * K + r0 + tx] = f2bf(tile[tx][r]);
  }
}

// ======== shared 128x128 MFMA mainloop (m97-style: BK=32, global_load_lds) ========
#define GEMM128_MAINLOOP(A, BT, m0, n0)                                                     \
  constexpr int K = 768;                                                                    \
  __shared__ u16 Asm[128 * 32];                                                             \
  __shared__ u16 Bsm[128 * 32];                                                             \
  const int tid = threadIdx.x;                                                              \
  const int w = tid >> 6, lane = tid & 63;                                                  \
  const int l15 = lane & 15, quad = lane >> 4;                                              \
  const int srow = tid >> 2, scol = (tid & 3) * 8;                                          \
  const u16* Ag0 = (A) + (size_t)((m0) + srow) * K + scol;                                  \
  const u16* Ag1 = (A) + (size_t)((m0) + 64 + srow) * K + scol;                             \
  const u16* Bg0 = (BT) + (size_t)((n0) + srow) * K + scol;                                 \
  const u16* Bg1 = (BT) + (size_t)((n0) + 64 + srow) * K + scol;                            \
  u16* Al0 = &Asm[(w * 64) * 8];                                                            \
  u16* Al1 = &Asm[(256 + w * 64) * 8];                                                      \
  u16* Bl0 = &Bsm[(w * 64) * 8];                                                            \
  u16* Bl1 = &Bsm[(256 + w * 64) * 8];                                                      \
  const int mw = (w >> 1) * 64, nw = (w & 1) * 64;                                          \
  f32x4 acc[4][4];                                                                          \
  _Pragma("unroll") for (int i = 0; i < 4; ++i) _Pragma("unroll") for (int j = 0; j < 4;    \
                                                                       ++j) acc[i][j] = {   \
      0.f, 0.f, 0.f, 0.f};                                                                  \
  for (int k0 = 0; k0 < K; k0 += 32) {                                                      \
    __syncthreads();                                                                        \
    gll16(Ag0 + k0, Al0);                                                                   \
    gll16(Ag1 + k0, Al1);                                                                   \
    gll16(Bg0 + k0, Bl0);                                                                   \
    gll16(Bg1 + k0, Bl1);                                                                   \
    __syncthreads();                                                                        \
    bf16x8 af[4], bfj[4];                                                                   \
    _Pragma("unroll") for (int i = 0; i < 4; ++i) af[i] =                                   \
        *(const bf16x8*)&Asm[(mw + i * 16 + l15) * 32 + quad * 8];                          \
    _Pragma("unroll") for (int j = 0; j < 4; ++j) bfj[j] =                                  \
        *(const bf16x8*)&Bsm[(nw + j * 16 + l15) * 32 + quad * 8];                          \
    _Pragma("unroll") for (int i = 0; i < 4; ++i) _Pragma("unroll") for (int j = 0; j < 4;  \
                                                                         ++j) acc[i][j] =  \
        __builtin_amdgcn_mfma_f32_16x16x32_bf16(af[i], bfj[j], acc[i][j], 0, 0, 0);         \
  }

// ---------------- QKV GEMM: [8192x768] x [768x2304] ----------------
__global__ __launch_bounds__(256) void gemm_qkv_kernel(
    const u16* __restrict__ A, const u16* __restrict__ BT, const float* __restrict__ bias,
    u16* __restrict__ Qb, u16* __restrict__ Kb, u16* __restrict__ Vt) {
  const int m0 = blockIdx.y * 128, n0 = blockIdx.x * 128;
  GEMM128_MAINLOOP(A, BT, m0, n0)
  const int sec = blockIdx.x / 6;           // 0:Q 1:K 2:V (uniform per block; 768%128==0)
  const int nbase = n0 - sec * 768;
#pragma unroll
  for (int j = 0; j < 4; ++j) {
    const int nloc = nbase + nw + j * 16 + l15;
    const float bv = bias[sec * 768 + nloc];
    const int h = nloc >> 6, d = nloc & 63;
#pragma unroll
    for (int i = 0; i < 4; ++i) {
      const int m = m0 + mw + i * 16 + quad * 4;
      const int bb = m >> 11, trow = m & 2047;
      if (sec == 2) {
        u64 pk = 0;
#pragma unroll
        for (int r = 0; r < 4; ++r) pk |= (u64)f2bf(acc[i][j][r] + bv) << (16 * r);
        *(u64*)(Vt + (size_t)((bb * 12 + h) * 64 + d) * 2048 + trow) = pk;
      } else {
        u16* dst = (sec == 0) ? Qb : Kb;
        const float scl = (sec == 0) ? 0.125f : 1.0f;
#pragma unroll
        for (int r = 0; r < 4; ++r)
          dst[(size_t)((bb * 12 + h) * 2048 + trow + r) * 64 + d] = f2bf((acc[i][j][r] + bv) * scl);
      }
    }
  }
}

// ---------------- proj GEMM: [8192x768] x [768x768], fp32 out + bias ----------------
__global__ __launch_bounds__(256) void gemm_proj_kernel(
    const u16* __restrict__ A, const u16* __restrict__ BT, const float* __restrict__ bias,
    float* __restrict__ out) {
  const int m0 = blockIdx.y * 128, n0 = blockIdx.x * 128;
  GEMM128_MAINLOOP(A, BT, m0, n0)
#pragma unroll
  for (int j = 0; j < 4; ++j) {
    const int n = n0 + nw + j * 16 + l15;
    const float bv = bias[n];
#pragma unroll
    for (int i = 0; i < 4; ++i) {
      const int m = m0 + mw + i * 16 + quad * 4;
#pragma unroll
      for (int r = 0; r < 4; ++r) out[(size_t)(m + r) * 768 + n] = acc[i][j][r] + bv;
    }
  }
}

// ---------------- causal flash attention, MFMA bf16 ----------------
// 128 q-rows/block (two 16-row groups per wave), reg-prefetched K/V staging.
// Q (pre-scaled) [bh][t][d]; K [bh][t][d]; Vt TRANSPOSED [bh][d][t]; out Yb bf16 [B][T][C]
__global__ __launch_bounds__(256) void attn_kernel(
    const u16* __restrict__ Qg, const u16* __restrict__ Kg, const u16* __restrict__ Vtg,
    u16* __restrict__ Yb) {
  constexpr int T = 2048, D = 64;
  constexpr int LDP = 72;
  __shared__ u16 Ks[64 * LDP];      // K tile  [k][d]
  __shared__ u16 VTs[64 * LDP];     // V^T tile [d][k]
  __shared__ u16 Ps[4 * 32 * LDP];  // P per-wave, 2 groups x [16 q][64 k]
  const int qb = 15 - blockIdx.x;   // descending work
  const int bh = blockIdx.y;
  const int Q0 = qb * 128;
  const int bidx = bh / 12, hidx = bh % 12;
  const int tid = threadIdx.x;
  const int w = tid >> 6, lane = tid & 63;
  const int l15 = lane & 15, quad = lane >> 4;
  const int srow = tid >> 2, scol = (tid & 3) * 16;  // 16 u16 = 32B per thread per array
  const u16* Kp = Kg + (size_t)bh * T * D;
  const u16* VTp = Vtg + (size_t)bh * D * T;
  u16* pw0 = &Ps[(w * 32) * LDP];
  u16* pw1 = &Ps[(w * 32 + 16) * LDP];

  // Q fragments (B-operand for S^T = K·Q^T), two 16-row groups
  const u16* qrow0 = Qg + ((size_t)bh * T + Q0 + w * 16 + l15) * D;
  const bf16x8 qf0a = *(const bf16x8*)(qrow0 + quad * 8);
  const bf16x8 qf0b = *(const bf16x8*)(qrow0 + 32 + quad * 8);
  const bf16x8 qf1a = *(const bf16x8*)(qrow0 + (size_t)64 * D + quad * 8);
  const bf16x8 qf1b = *(const bf16x8*)(qrow0 + (size_t)64 * D + 32 + quad * 8);
  const int qq0 = Q0 + w * 16 + l15, qq1 = qq0 + 64;

  f32x4 o0[4] = {{0,0,0,0},{0,0,0,0},{0,0,0,0},{0,0,0,0}};
  f32x4 o1[4] = {{0,0,0,0},{0,0,0,0},{0,0,0,0},{0,0,0,0}};
  float m0v = -1e30f, l0v = 0.f, m1v = -1e30f, l1v = 0.f;

  const int nkt = 2 * qb + 2;
  // prefetch tile 0
  u32x4 kA = *(const u32x4*)(Kp + (size_t)srow * D + scol);
  u32x4 kB = *(const u32x4*)(Kp + (size_t)srow * D + scol + 8);
  u32x4 vA = *(const u32x4*)(VTp + (size_t)srow * T + scol);
  u32x4 vB = *(const u32x4*)(VTp + (size_t)srow * T + scol + 8);

  for (int kt = 0; kt < nkt; ++kt) {
    __syncthreads();  // all waves done with Ks/VTs
    *(u32x4*)&Ks[srow * LDP + scol] = kA;
    *(u32x4*)&Ks[srow * LDP + scol + 8] = kB;
    *(u32x4*)&VTs[srow * LDP + scol] = vA;
    *(u32x4*)&VTs[srow * LDP + scol + 8] = vB;
    __syncthreads();
    if (kt + 1 < nkt) {  // prefetch next tile; latency overlaps compute below
      const int k1 = (kt + 1) * 64;
      kA = *(const u32x4*)(Kp + (size_t)(k1 + srow) * D + scol);
      kB = *(const u32x4*)(Kp + (size_t)(k1 + srow) * D + scol + 8);
      vA = *(const u32x4*)(VTp + (size_t)srow * T + k1 + scol);
      vB = *(const u32x4*)(VTp + (size_t)srow * T + k1 + scol + 8);
    }
    const int k0 = kt * 64;
    const bool g0a = (kt <= 2 * qb);  // group 0 inactive on the final tile

    // S^T = K·Q^T for both q-groups; K-frags shared
    f32x4 s0[4] = {{0,0,0,0},{0,0,0,0},{0,0,0,0},{0,0,0,0}};
    f32x4 s1[4] = {{0,0,0,0},{0,0,0,0},{0,0,0,0},{0,0,0,0}};
#pragma unroll
    for (int t = 0; t < 4; ++t) {
      const bf16x8 kf0 = *(const bf16x8*)&Ks[(t * 16 + l15) * LDP + quad * 8];
      const bf16x8 kf1 = *(const bf16x8*)&Ks[(t * 16 + l15) * LDP + 32 + quad * 8];
      s0[t] = __builtin_amdgcn_mfma_f32_16x16x32_bf16(kf0, qf0a, s0[t], 0, 0, 0);
      s0[t] = __builtin_amdgcn_mfma_f32_16x16x32_bf16(kf1, qf0b, s0[t], 0, 0, 0);
      s1[t] = __builtin_amdgcn_mfma_f32_16x16x32_bf16(kf0, qf1a, s1[t], 0, 0, 0);
      s1[t] = __builtin_amdgcn_mfma_f32_16x16x32_bf16(kf1, qf1b, s1[t], 0, 0, 0);
    }
    // ---- softmax group 0 ----
    if (g0a) {
      if (kt == 2 * qb) {  // diagonal for g0
#pragma unroll
        for (int t = 0; t < 4; ++t)
#pragma unroll
          for (int r = 0; r < 4; ++r)
            if (k0 + t * 16 + quad * 4 + r > qq0) s0[t][r] = -1e30f;
      }
      float lm = -1e30f;
#pragma unroll
      for (int t = 0; t < 4; ++t)
#pragma unroll
        for (int r = 0; r < 4; ++r) lm = fmaxf(lm, s0[t][r]);
      lm = fmaxf(lm, __shfl_xor(lm, 16));
      lm = fmaxf(lm, __shfl_xor(lm, 32));
      const float nm = fmaxf(m0v, lm);
      const float alpha = __expf(m0v - nm);
      m0v = nm;
      float ls = 0.f;
#pragma unroll
      for (int t = 0; t < 4; ++t) {
        u64 pk = 0;
#pragma unroll
        for (int r = 0; r < 4; ++r) {
          const u16 pb = f2bf(__expf(s0[t][r] - nm));
          ls += bflo(pb);
          pk |= (u64)pb << (16 * r);
        }
        *(u64*)&pw0[l15 * LDP + t * 16 + quad * 4] = pk;
      }
      ls += __shfl_xor(ls, 16);
      ls += __shfl_xor(ls, 32);
      l0v = l0v * alpha + ls;
      float ar[4];
#pragma unroll
      for (int r = 0; r < 4; ++r) ar[r] = __shfl(alpha, (quad << 4) | (quad * 4 + r));
#pragma unroll
      for (int t = 0; t < 4; ++t)
#pragma unroll
        for (int r = 0; r < 4; ++r) o0[t][r] *= ar[r];
    }
    // ---- softmax group 1 ----
    {
      if (kt == 2 * qb + 1) {  // diagonal for g1
#pragma unroll
        for (int t = 0; t < 4; ++t)
#pragma unroll
          for (int r = 0; r < 4; ++r)
            if (k0 + t * 16 + quad * 4 + r > qq1) s1[t][r] = -1e30f;
      }
      float lm = -1e30f;
#pragma unroll
      for (int t = 0; t < 4; ++t)
#pragma unroll
        for (int r = 0; r < 4; ++r) lm = fmaxf(lm, s1[t][r]);
      lm = fmaxf(lm, __shfl_xor(lm, 16));
      lm = fmaxf(lm, __shfl_xor(lm, 32));
      const float nm = fmaxf(m1v, lm);
      const float alpha = __expf(m1v - nm);
      m1v = nm;
      float ls = 0.f;
#pragma unroll
      for (int t = 0; t < 4; ++t) {
        u64 pk = 0;
#pragma unroll
        for (int r = 0; r < 4; ++r) {
          const u16 pb = f2bf(__expf(s1[t][r] - nm));
          ls += bflo(pb);
          pk |= (u64)pb << (16 * r);
        }
        *(u64*)&pw1[l15 * LDP + t * 16 + quad * 4] = pk;
      }
      ls += __shfl_xor(ls, 16);
      ls += __shfl_xor(ls, 32);
      l1v = l1v * alpha + ls;
      float ar[4];
#pragma unroll
      for (int r = 0; r < 4; ++r) ar[r] = __shfl(alpha, (quad << 4) | (quad * 4 + r));
#pragma unroll
      for (int t = 0; t < 4; ++t)
#pragma unroll
        for (int r = 0; r < 4; ++r) o1[t][r] *= ar[r];
    }
    // ---- PV for both groups; V-frags shared ----
    const bf16x8 p0a = *(const bf16x8*)&pw0[l15 * LDP + quad * 8];
    const bf16x8 p0b = *(const bf16x8*)&pw0[l15 * LDP + 32 + quad * 8];
    const bf16x8 p1a = *(const bf16x8*)&pw1[l15 * LDP + quad * 8];
    const bf16x8 p1b = *(const bf16x8*)&pw1[l15 * LDP + 32 + quad * 8];
#pragma unroll
    for (int t = 0; t < 4; ++t) {
      const bf16x8 vf0 = *(const bf16x8*)&VTs[(t * 16 + l15) * LDP + quad * 8];
      const bf16x8 vf1 = *(const bf16x8*)&VTs[(t * 16 + l15) * LDP + 32 + quad * 8];
      if (g0a) {
        o0[t] = __builtin_amdgcn_mfma_f32_16x16x32_bf16(p0a, vf0, o0[t], 0, 0, 0);
        o0[t] = __builtin_amdgcn_mfma_f32_16x16x32_bf16(p0b, vf1, o0[t], 0, 0, 0);
      }
      o1[t] = __builtin_amdgcn_mfma_f32_16x16x32_bf16(p1a, vf0, o1[t], 0, 0, 0);
      o1[t] = __builtin_amdgcn_mfma_f32_16x16x32_bf16(p1b, vf1, o1[t], 0, 0, 0);
    }
  }
  // epilogue: both groups
#pragma unroll
  for (int r = 0; r < 4; ++r) {
    const float lr0 = __shfl(l0v, (quad << 4) | (quad * 4 + r));
    const float lr1 = __shfl(l1v, (quad << 4) | (quad * 4 + r));
    const float inv0 = 1.f / lr0, inv1 = 1.f / lr1;
    const int q0r = Q0 + w * 16 + quad * 4 + r;
    u16* y0 = Yb + ((size_t)bidx * T + q0r) * 768 + hidx * 64;
    u16* y1 = Yb + ((size_t)bidx * T + q0r + 64) * 768 + hidx * 64;
#pragma unroll
    for (int t = 0; t < 4; ++t) {
      y0[t * 16 + l15] = f2bf(o0[t][r] * inv0);
      y1[t * 16 + l15] = f2bf(o1[t][r] * inv1);
    }
  }
}

extern "C" void kernel_launch(void* const* d_in, const int* in_sizes, int n_in,
                              void* d_out, int out_size, void* d_ws, size_t ws_size,
                              hipStream_t stream) {
  const float* x = (const float*)d_in[0];
  const float* W_qkv = (const float*)d_in[1];
  const float* b_qkv = (const float*)d_in[2];
  const float* W_proj = (const float*)d_in[3];
  const float* b_proj = (const float*)d_in[4];
  float* out = (float*)d_out;

  constexpr size_t MC = (size_t)8192 * 768;
  u16* xb = (u16*)d_ws;
  u16* Qb = xb + MC;
  u16* Kb = Qb + MC;
  u16* Vt = Kb + MC;   // transposed V: [bh][d][t]
  u16* Yb = Vt + MC;
  u16* WqkvT = Yb + MC;
  u16* WprojT = WqkvT + (size_t)2304 * 768;

  cast_x_kernel<<<6291456 / (4 * 256), 256, 0, stream>>>(x, xb, 6291456 / 4);
  transpose_cast_kernel<<<dim3(2304 / 32, 768 / 32), 256, 0, stream>>>(W_qkv, WqkvT, 768, 2304);
  transpose_cast_kernel<<<dim3(768 / 32, 768 / 32), 256, 0, stream>>>(W_proj, WprojT, 768, 768);
  gemm_qkv_kernel<<<dim3(18, 64), 256, 0, stream>>>(xb, WqkvT, b_qkv, Qb, Kb, Vt);
  attn_kernel<<<dim3(16, 48), 256, 0, stream>>>(Qb, Kb, Vt, Yb);
  gemm_proj_kernel<<<dim3(6, 64), 256, 0, stream>>>(Yb, WprojT, b_proj, out);
}

// Round 5
// 267.483 us; speedup vs baseline: 3.3908x; 1.1222x over previous
//
#include <hip/hip_runtime.h>

typedef __bf16 bf16x8 __attribute__((ext_vector_type(8)));
typedef float f32x4 __attribute__((ext_vector_type(4)));
typedef unsigned int u32x4 __attribute__((ext_vector_type(4)));
typedef unsigned short u16;
typedef unsigned long long u64;

__device__ __forceinline__ u16 f2bf(float f) {
  unsigned u = __builtin_bit_cast(unsigned, f);
  u += 0x7FFFu + ((u >> 16) & 1u);   // RNE
  return (u16)(u >> 16);
}
__device__ __forceinline__ float bflo(unsigned u) { return __builtin_bit_cast(float, u << 16); }

// async global->LDS direct copy, 16B per lane. LDS dest = wave-uniform base + lane*16.
__device__ __forceinline__ void gll16(const u16* g, u16* l) {
  __builtin_amdgcn_global_load_lds(
      (const __attribute__((address_space(1))) unsigned int*)g,
      (__attribute__((address_space(3))) unsigned int*)l, 16, 0, 0);
}

// ---------------- cast x (fp32 -> bf16), vectorized ----------------
__global__ void cast_x_kernel(const float* __restrict__ in, u16* __restrict__ out, int n4) {
  int i = blockIdx.x * blockDim.x + threadIdx.x;
  if (i >= n4) return;
  f32x4 v = *(const f32x4*)(in + (size_t)i * 4);
  u64 pk = (u64)f2bf(v[0]) | ((u64)f2bf(v[1]) << 16) | ((u64)f2bf(v[2]) << 32) | ((u64)f2bf(v[3]) << 48);
  *(u64*)(out + (size_t)i * 4) = pk;
}

// ------------- transpose + cast: W[K][N] fp32 -> WT[N][K] bf16 -------------
__global__ void transpose_cast_kernel(const float* __restrict__ W, u16* __restrict__ WT, int K, int N) {
  __shared__ float tile[32][33];
  int c0 = blockIdx.x * 32, r0 = blockIdx.y * 32;
  int tx = threadIdx.x & 31, tg = threadIdx.x >> 5;
#pragma unroll
  for (int i = 0; i < 4; ++i) {
    int r = tg + i * 8;
    tile[r][tx] = W[(size_t)(r0 + r) * N + c0 + tx];
  }
  __syncthreads();
#pragma unroll
  for (int i = 0; i < 4; ++i) {
    int r = tg + i * 8;
    WT[(size_t)(c0 + r) * K + r0 + tx] = f2bf(tile[tx][r]);
  }
}

// ======== shared 128x128 MFMA mainloop (m97-style: BK=32, global_load_lds) ========
#define GEMM128_MAINLOOP(A, BT, m0, n0)                                                     \
  constexpr int K = 768;                                                                    \
  __shared__ u16 Asm[128 * 32];                                                             \
  __shared__ u16 Bsm[128 * 32];                                                             \
  const int tid = threadIdx.x;                                                              \
  const int w = tid >> 6, lane = tid & 63;                                                  \
  const int l15 = lane & 15, quad = lane >> 4;                                              \
  const int srow = tid >> 2, scol = (tid & 3) * 8;                                          \
  const u16* Ag0 = (A) + (size_t)((m0) + srow) * K + scol;                                  \
  const u16* Ag1 = (A) + (size_t)((m0) + 64 + srow) * K + scol;                             \
  const u16* Bg0 = (BT) + (size_t)((n0) + srow) * K + scol;                                 \
  const u16* Bg1 = (BT) + (size_t)((n0) + 64 + srow) * K + scol;                            \
  u16* Al0 = &Asm[(w * 64) * 8];                                                            \
  u16* Al1 = &Asm[(256 + w * 64) * 8];                                                      \
  u16* Bl0 = &Bsm[(w * 64) * 8];                                                            \
  u16* Bl1 = &Bsm[(256 + w * 64) * 8];                                                      \
  const int mw = (w >> 1) * 64, nw = (w & 1) * 64;                                          \
  f32x4 acc[4][4];                                                                          \
  _Pragma("unroll") for (int i = 0; i < 4; ++i) _Pragma("unroll") for (int j = 0; j < 4;    \
                                                                       ++j) acc[i][j] = {   \
      0.f, 0.f, 0.f, 0.f};                                                                  \
  for (int k0 = 0; k0 < K; k0 += 32) {                                                      \
    __syncthreads();                                                                        \
    gll16(Ag0 + k0, Al0);                                                                   \
    gll16(Ag1 + k0, Al1);                                                                   \
    gll16(Bg0 + k0, Bl0);                                                                   \
    gll16(Bg1 + k0, Bl1);                                                                   \
    __syncthreads();                                                                        \
    bf16x8 af[4], bfj[4];                                                                   \
    _Pragma("unroll") for (int i = 0; i < 4; ++i) af[i] =                                   \
        *(const bf16x8*)&Asm[(mw + i * 16 + l15) * 32 + quad * 8];                          \
    _Pragma("unroll") for (int j = 0; j < 4; ++j) bfj[j] =                                  \
        *(const bf16x8*)&Bsm[(nw + j * 16 + l15) * 32 + quad * 8];                          \
    _Pragma("unroll") for (int i = 0; i < 4; ++i) _Pragma("unroll") for (int j = 0; j < 4;  \
                                                                         ++j) acc[i][j] =  \
        __builtin_amdgcn_mfma_f32_16x16x32_bf16(af[i], bfj[j], acc[i][j], 0, 0, 0);         \
  }

// ---------------- QKV GEMM: [8192x768] x [768x2304] ----------------
// Q pre-scaled by 0.125*log2(e) (exp2-domain attention). V written TRANSPOSED: Vt[bh][d][t].
__global__ __launch_bounds__(256) void gemm_qkv_kernel(
    const u16* __restrict__ A, const u16* __restrict__ BT, const float* __restrict__ bias,
    u16* __restrict__ Qb, u16* __restrict__ Kb, u16* __restrict__ Vt) {
  const int m0 = blockIdx.y * 128, n0 = blockIdx.x * 128;
  GEMM128_MAINLOOP(A, BT, m0, n0)
  const int sec = blockIdx.x / 6;           // 0:Q 1:K 2:V (uniform per block; 768%128==0)
  const int nbase = n0 - sec * 768;
#pragma unroll
  for (int j = 0; j < 4; ++j) {
    const int nloc = nbase + nw + j * 16 + l15;
    const float bv = bias[sec * 768 + nloc];
    const int h = nloc >> 6, d = nloc & 63;
#pragma unroll
    for (int i = 0; i < 4; ++i) {
      const int m = m0 + mw + i * 16 + quad * 4;
      const int bb = m >> 11, trow = m & 2047;
      if (sec == 2) {
        u64 pk = 0;
#pragma unroll
        for (int r = 0; r < 4; ++r) pk |= (u64)f2bf(acc[i][j][r] + bv) << (16 * r);
        *(u64*)(Vt + (size_t)((bb * 12 + h) * 64 + d) * 2048 + trow) = pk;
      } else {
        u16* dst = (sec == 0) ? Qb : Kb;
        const float scl = (sec == 0) ? 0.125f * 1.44269504f : 1.0f;
#pragma unroll
        for (int r = 0; r < 4; ++r)
          dst[(size_t)((bb * 12 + h) * 2048 + trow + r) * 64 + d] = f2bf((acc[i][j][r] + bv) * scl);
      }
    }
  }
}

// ---------------- proj GEMM: [8192x768] x [768x768], fp32 out + bias ----------------
__global__ __launch_bounds__(256) void gemm_proj_kernel(
    const u16* __restrict__ A, const u16* __restrict__ BT, const float* __restrict__ bias,
    float* __restrict__ out) {
  const int m0 = blockIdx.y * 128, n0 = blockIdx.x * 128;
  GEMM128_MAINLOOP(A, BT, m0, n0)
#pragma unroll
  for (int j = 0; j < 4; ++j) {
    const int n = n0 + nw + j * 16 + l15;
    const float bv = bias[n];
#pragma unroll
    for (int i = 0; i < 4; ++i) {
      const int m = m0 + mw + i * 16 + quad * 4;
#pragma unroll
      for (int r = 0; r < 4; ++r) out[(size_t)(m + r) * 768 + n] = acc[i][j][r] + bv;
    }
  }
}

// ---------------- causal flash attention, MFMA bf16, fixed-max exp2 softmax ----------------
// 128 q-rows/block (two 16-row groups/wave). Scores s' = q·k·0.125·log2e; p = 2^(s'-M).
// No online max: M=20 static bound (scores ~N(0,1.44), max<<20). No per-iter shuffles.
// O^T = V^T·P^T (operand-swapped MFMA) -> shfl-free normalization + vectorized stores.
__global__ __launch_bounds__(256) void attn_kernel(
    const u16* __restrict__ Qg, const u16* __restrict__ Kg, const u16* __restrict__ Vtg,
    u16* __restrict__ Yb) {
  constexpr int T = 2048, D = 64;
  constexpr int LDP = 72;
  constexpr float MBOUND = 20.0f;  // exp2-domain static max bound
  __shared__ u16 Ks[64 * LDP];      // K tile  [k][d]
  __shared__ u16 VTs[64 * LDP];     // V^T tile [d][k]
  __shared__ u16 Ps[4 * 32 * LDP];  // P per-wave, 2 groups x [16 q][64 k]
  const int qb = 15 - blockIdx.x;   // descending work (LPT)
  const int bh = blockIdx.y;
  const int Q0 = qb * 128;
  const int bidx = bh / 12, hidx = bh % 12;
  const int tid = threadIdx.x;
  const int w = tid >> 6, lane = tid & 63;
  const int l15 = lane & 15, quad = lane >> 4;
  const int srow = tid >> 2, scol = (tid & 3) * 16;
  const u16* Kp = Kg + (size_t)bh * T * D;
  const u16* VTp = Vtg + (size_t)bh * D * T;
  u16* pw0 = &Ps[(w * 32) * LDP];
  u16* pw1 = &Ps[(w * 32 + 16) * LDP];

  // Q fragments (B-operand for S^T = K·Q^T), two 16-row groups
  const u16* qrow0 = Qg + ((size_t)bh * T + Q0 + w * 16 + l15) * D;
  const bf16x8 qf0a = *(const bf16x8*)(qrow0 + quad * 8);
  const bf16x8 qf0b = *(const bf16x8*)(qrow0 + 32 + quad * 8);
  const bf16x8 qf1a = *(const bf16x8*)(qrow0 + (size_t)64 * D + quad * 8);
  const bf16x8 qf1b = *(const bf16x8*)(qrow0 + (size_t)64 * D + 32 + quad * 8);
  const int qq0 = Q0 + w * 16 + l15, qq1 = qq0 + 64;

  f32x4 o0[4] = {{0,0,0,0},{0,0,0,0},{0,0,0,0},{0,0,0,0}};  // O^T: row=d, col=q=l15
  f32x4 o1[4] = {{0,0,0,0},{0,0,0,0},{0,0,0,0},{0,0,0,0}};
  float l0v = 0.f, l1v = 0.f;  // per-lane partial denominators (this quad's k-chunks)

  const int nkt = 2 * qb + 2;
  // prefetch tile 0 into registers
  u32x4 kA = *(const u32x4*)(Kp + (size_t)srow * D + scol);
  u32x4 kB = *(const u32x4*)(Kp + (size_t)srow * D + scol + 8);
  u32x4 vA = *(const u32x4*)(VTp + (size_t)srow * T + scol);
  u32x4 vB = *(const u32x4*)(VTp + (size_t)srow * T + scol + 8);

  for (int kt = 0; kt < nkt; ++kt) {
    __syncthreads();  // all waves done with Ks/VTs
    *(u32x4*)&Ks[srow * LDP + scol] = kA;
    *(u32x4*)&Ks[srow * LDP + scol + 8] = kB;
    *(u32x4*)&VTs[srow * LDP + scol] = vA;
    *(u32x4*)&VTs[srow * LDP + scol + 8] = vB;
    __syncthreads();
    if (kt + 1 < nkt) {  // prefetch next tile; latency overlaps compute below
      const int k1 = (kt + 1) * 64;
      kA = *(const u32x4*)(Kp + (size_t)(k1 + srow) * D + scol);
      kB = *(const u32x4*)(Kp + (size_t)(k1 + srow) * D + scol + 8);
      vA = *(const u32x4*)(VTp + (size_t)srow * T + k1 + scol);
      vB = *(const u32x4*)(VTp + (size_t)srow * T + k1 + scol + 8);
    }
    const int k0 = kt * 64;
    const bool g0a = (kt <= 2 * qb);  // group 0 inactive on the final tile

    // S^T = K·Q^T for both q-groups; K-frags shared
    f32x4 s0[4] = {{0,0,0,0},{0,0,0,0},{0,0,0,0},{0,0,0,0}};
    f32x4 s1[4] = {{0,0,0,0},{0,0,0,0},{0,0,0,0},{0,0,0,0}};
#pragma unroll
    for (int t = 0; t < 4; ++t) {
      const bf16x8 kf0 = *(const bf16x8*)&Ks[(t * 16 + l15) * LDP + quad * 8];
      const bf16x8 kf1 = *(const bf16x8*)&Ks[(t * 16 + l15) * LDP + 32 + quad * 8];
      s0[t] = __builtin_amdgcn_mfma_f32_16x16x32_bf16(kf0, qf0a, s0[t], 0, 0, 0);
      s0[t] = __builtin_amdgcn_mfma_f32_16x16x32_bf16(kf1, qf0b, s0[t], 0, 0, 0);
      s1[t] = __builtin_amdgcn_mfma_f32_16x16x32_bf16(kf0, qf1a, s1[t], 0, 0, 0);
      s1[t] = __builtin_amdgcn_mfma_f32_16x16x32_bf16(kf1, qf1b, s1[t], 0, 0, 0);
    }
    // ---- fixed-max softmax, group 0: p = 2^(s-M); no cross-lane ops ----
    if (g0a) {
      if (kt == 2 * qb) {  // diagonal for g0
#pragma unroll
        for (int t = 0; t < 4; ++t)
#pragma unroll
          for (int r = 0; r < 4; ++r)
            if (k0 + t * 16 + quad * 4 + r > qq0) s0[t][r] = -1e30f;
      }
#pragma unroll
      for (int t = 0; t < 4; ++t) {
        u64 pk = 0;
#pragma unroll
        for (int r = 0; r < 4; ++r) {
          const u16 pb = f2bf(__builtin_amdgcn_exp2f(s0[t][r] - MBOUND));
          l0v += bflo(pb);  // sum bf16-rounded: consistent with PV numerator
          pk |= (u64)pb << (16 * r);
        }
        *(u64*)&pw0[l15 * LDP + t * 16 + quad * 4] = pk;
      }
    }
    // ---- group 1 ----
    {
      if (kt == 2 * qb + 1) {  // diagonal for g1
#pragma unroll
        for (int t = 0; t < 4; ++t)
#pragma unroll
          for (int r = 0; r < 4; ++r)
            if (k0 + t * 16 + quad * 4 + r > qq1) s1[t][r] = -1e30f;
      }
#pragma unroll
      for (int t = 0; t < 4; ++t) {
        u64 pk = 0;
#pragma unroll
        for (int r = 0; r < 4; ++r) {
          const u16 pb = f2bf(__builtin_amdgcn_exp2f(s1[t][r] - MBOUND));
          l1v += bflo(pb);
          pk |= (u64)pb << (16 * r);
        }
        *(u64*)&pw1[l15 * LDP + t * 16 + quad * 4] = pk;
      }
    }
    // ---- O^T += V^T·P^T for both groups; V-frags (A-operand) shared ----
    const bf16x8 p0a = *(const bf16x8*)&pw0[l15 * LDP + quad * 8];
    const bf16x8 p0b = *(const bf16x8*)&pw0[l15 * LDP + 32 + quad * 8];
    const bf16x8 p1a = *(const bf16x8*)&pw1[l15 * LDP + quad * 8];
    const bf16x8 p1b = *(const bf16x8*)&pw1[l15 * LDP + 32 + quad * 8];
#pragma unroll
    for (int t = 0; t < 4; ++t) {
      const bf16x8 vf0 = *(const bf16x8*)&VTs[(t * 16 + l15) * LDP + quad * 8];
      const bf16x8 vf1 = *(const bf16x8*)&VTs[(t * 16 + l15) * LDP + 32 + quad * 8];
      if (g0a) {
        o0[t] = __builtin_amdgcn_mfma_f32_16x16x32_bf16(vf0, p0a, o0[t], 0, 0, 0);
        o0[t] = __builtin_amdgcn_mfma_f32_16x16x32_bf16(vf1, p0b, o0[t], 0, 0, 0);
      }
      o1[t] = __builtin_amdgcn_mfma_f32_16x16x32_bf16(vf0, p1a, o1[t], 0, 0, 0);
      o1[t] = __builtin_amdgcn_mfma_f32_16x16x32_bf16(vf1, p1b, o1[t], 0, 0, 0);
    }
  }
  // final l reduction (once): sum the 4 quad partials for this lane's q=l15
  l0v += __shfl_xor(l0v, 16); l0v += __shfl_xor(l0v, 32);
  l1v += __shfl_xor(l1v, 16); l1v += __shfl_xor(l1v, 32);
  const float inv0 = 1.f / l0v, inv1 = 1.f / l1v;
  // epilogue: O^T rows are d=16t+quad*4+r, col q=l15 -> u64 stores along d
  u16* y0 = Yb + ((size_t)bidx * T + qq0) * 768 + hidx * 64;
  u16* y1 = Yb + ((size_t)bidx * T + qq1) * 768 + hidx * 64;
#pragma unroll
  for (int t = 0; t < 4; ++t) {
    u64 pk0 = 0, pk1 = 0;
#pragma unroll
    for (int r = 0; r < 4; ++r) {
      pk0 |= (u64)f2bf(o0[t][r] * inv0) << (16 * r);
      pk1 |= (u64)f2bf(o1[t][r] * inv1) << (16 * r);
    }
    *(u64*)(y0 + t * 16 + quad * 4) = pk0;
    *(u64*)(y1 + t * 16 + quad * 4) = pk1;
  }
}

extern "C" void kernel_launch(void* const* d_in, const int* in_sizes, int n_in,
                              void* d_out, int out_size, void* d_ws, size_t ws_size,
                              hipStream_t stream) {
  const float* x = (const float*)d_in[0];
  const float* W_qkv = (const float*)d_in[1];
  const float* b_qkv = (const float*)d_in[2];
  const float* W_proj = (const float*)d_in[3];
  const float* b_proj = (const float*)d_in[4];
  float* out = (float*)d_out;

  constexpr size_t MC = (size_t)8192 * 768;
  u16* xb = (u16*)d_ws;
  u16* Qb = xb + MC;
  u16* Kb = Qb + MC;
  u16* Vt = Kb + MC;   // transposed V: [bh][d][t]
  u16* Yb = Vt + MC;
  u16* WqkvT = Yb + MC;
  u16* WprojT = WqkvT + (size_t)2304 * 768;

  cast_x_kernel<<<6291456 / (4 * 256), 256, 0, stream>>>(x, xb, 6291456 / 4);
  transpose_cast_kernel<<<dim3(2304 / 32, 768 / 32), 256, 0, stream>>>(W_qkv, WqkvT, 768, 2304);
  transpose_cast_kernel<<<dim3(768 / 32, 768 / 32), 256, 0, stream>>>(W_proj, WprojT, 768, 768);
  gemm_qkv_kernel<<<dim3(18, 64), 256, 0, stream>>>(xb, WqkvT, b_qkv, Qb, Kb, Vt);
  attn_kernel<<<dim3(16, 48), 256, 0, stream>>>(Qb, Kb, Vt, Yb);
  gemm_proj_kernel<<<dim3(6, 64), 256, 0, stream>>>(Yb, WprojT, b_proj, out);
}

// Round 7
// 261.998 us; speedup vs baseline: 3.4618x; 1.0209x over previous
//
#include <hip/hip_runtime.h>
#include <hip/hip_bf16.h>

typedef __bf16 bf16x8 __attribute__((ext_vector_type(8)));
typedef float f32x4 __attribute__((ext_vector_type(4)));
typedef unsigned int u32x4 __attribute__((ext_vector_type(4)));
typedef unsigned int u32x2 __attribute__((ext_vector_type(2)));
typedef unsigned short u16;
typedef unsigned long long u64;

__device__ __forceinline__ u16 f2bf(float f) {
  unsigned u = __builtin_bit_cast(unsigned, f);
  u += 0x7FFFu + ((u >> 16) & 1u);   // RNE
  return (u16)(u >> 16);
}
// HW packed convert: 2 fp32 -> 2 bf16 in one v_cvt_pk_bf16_f32 (RNE)
__device__ __forceinline__ unsigned cvtpk(float a, float b) {
  float2 f; f.x = a; f.y = b;
  __hip_bfloat162 h = __float22bfloat162_rn(f);
  unsigned u;
  __builtin_memcpy(&u, &h, 4);
  return u;
}

// async global->LDS direct copy, 16B per lane. LDS dest = wave-uniform base + lane*16.
__device__ __forceinline__ void gll16(const u16* g, u16* l) {
  __builtin_amdgcn_global_load_lds(
      (const __attribute__((address_space(1))) unsigned int*)g,
      (__attribute__((address_space(3))) unsigned int*)l, 16, 0, 0);
}

// ---------------- cast x (fp32 -> bf16), vectorized ----------------
__global__ void cast_x_kernel(const float* __restrict__ in, u16* __restrict__ out, int n4) {
  int i = blockIdx.x * blockDim.x + threadIdx.x;
  if (i >= n4) return;
  f32x4 v = *(const f32x4*)(in + (size_t)i * 4);
  u32x2 pk;
  pk[0] = cvtpk(v[0], v[1]);
  pk[1] = cvtpk(v[2], v[3]);
  *(u32x2*)(out + (size_t)i * 4) = pk;
}

// ------------- transpose + cast: W[K][N] fp32 -> WT[N][K] bf16 -------------
__global__ void transpose_cast_kernel(const float* __restrict__ W, u16* __restrict__ WT, int K, int N) {
  __shared__ float tile[32][33];
  int c0 = blockIdx.x * 32, r0 = blockIdx.y * 32;
  int tx = threadIdx.x & 31, tg = threadIdx.x >> 5;
#pragma unroll
  for (int i = 0; i < 4; ++i) {
    int r = tg + i * 8;
    tile[r][tx] = W[(size_t)(r0 + r) * N + c0 + tx];
  }
  __syncthreads();
#pragma unroll
  for (int i = 0; i < 4; ++i) {
    int r = tg + i * 8;
    WT[(size_t)(c0 + r) * K + r0 + tx] = f2bf(tile[tx][r]);
  }
}

// ======== shared 128x128 MFMA mainloop (m97-style: BK=32, global_load_lds) ========
#define GEMM128_MAINLOOP(A, BT, m0, n0)                                                     \
  constexpr int K = 768;                                                                    \
  __shared__ u16 Asm[128 * 32];                                                             \
  __shared__ u16 Bsm[128 * 32];                                                             \
  const int tid = threadIdx.x;                                                              \
  const int w = tid >> 6, lane = tid & 63;                                                  \
  const int l15 = lane & 15, quad = lane >> 4;                                              \
  const int srow = tid >> 2, scol = (tid & 3) * 8;                                          \
  const u16* Ag0 = (A) + (size_t)((m0) + srow) * K + scol;                                  \
  const u16* Ag1 = (A) + (size_t)((m0) + 64 + srow) * K + scol;                             \
  const u16* Bg0 = (BT) + (size_t)((n0) + srow) * K + scol;                                 \
  const u16* Bg1 = (BT) + (size_t)((n0) + 64 + srow) * K + scol;                            \
  u16* Al0 = &Asm[(w * 64) * 8];                                                            \
  u16* Al1 = &Asm[(256 + w * 64) * 8];                                                      \
  u16* Bl0 = &Bsm[(w * 64) * 8];                                                            \
  u16* Bl1 = &Bsm[(256 + w * 64) * 8];                                                      \
  const int mw = (w >> 1) * 64, nw = (w & 1) * 64;                                          \
  f32x4 acc[4][4];                                                                          \
  _Pragma("unroll") for (int i = 0; i < 4; ++i) _Pragma("unroll") for (int j = 0; j < 4;    \
                                                                       ++j) acc[i][j] = {   \
      0.f, 0.f, 0.f, 0.f};                                                                  \
  for (int k0 = 0; k0 < K; k0 += 32) {                                                      \
    __syncthreads();                                                                        \
    gll16(Ag0 + k0, Al0);                                                                   \
    gll16(Ag1 + k0, Al1);                                                                   \
    gll16(Bg0 + k0, Bl0);                                                                   \
    gll16(Bg1 + k0, Bl1);                                                                   \
    __syncthreads();                                                                        \
    bf16x8 af[4], bfj[4];                                                                   \
    _Pragma("unroll") for (int i = 0; i < 4; ++i) af[i] =                                   \
        *(const bf16x8*)&Asm[(mw + i * 16 + l15) * 32 + quad * 8];                          \
    _Pragma("unroll") for (int j = 0; j < 4; ++j) bfj[j] =                                  \
        *(const bf16x8*)&Bsm[(nw + j * 16 + l15) * 32 + quad * 8];                          \
    _Pragma("unroll") for (int i = 0; i < 4; ++i) _Pragma("unroll") for (int j = 0; j < 4;  \
                                                                         ++j) acc[i][j] =  \
        __builtin_amdgcn_mfma_f32_16x16x32_bf16(af[i], bfj[j], acc[i][j], 0, 0, 0);         \
  }

// ---------------- QKV GEMM: [8192x768] x [768x2304] ----------------
// Q pre-scaled by 0.125*log2(e) (exp2-domain attention). V written TRANSPOSED: Vt[bh][d][t].
__global__ __launch_bounds__(256) void gemm_qkv_kernel(
    const u16* __restrict__ A, const u16* __restrict__ BT, const float* __restrict__ bias,
    u16* __restrict__ Qb, u16* __restrict__ Kb, u16* __restrict__ Vt) {
  const int m0 = blockIdx.y * 128, n0 = blockIdx.x * 128;
  GEMM128_MAINLOOP(A, BT, m0, n0)
  const int sec = blockIdx.x / 6;           // 0:Q 1:K 2:V (uniform per block; 768%128==0)
  const int nbase = n0 - sec * 768;
#pragma unroll
  for (int j = 0; j < 4; ++j) {
    const int nloc = nbase + nw + j * 16 + l15;
    const float bv = bias[sec * 768 + nloc];
    const int h = nloc >> 6, d = nloc & 63;
#pragma unroll
    for (int i = 0; i < 4; ++i) {
      const int m = m0 + mw + i * 16 + quad * 4;
      const int bb = m >> 11, trow = m & 2047;
      if (sec == 2) {
        u32x2 pk;
        pk[0] = cvtpk(acc[i][j][0] + bv, acc[i][j][1] + bv);
        pk[1] = cvtpk(acc[i][j][2] + bv, acc[i][j][3] + bv);
        *(u32x2*)(Vt + (size_t)((bb * 12 + h) * 64 + d) * 2048 + trow) = pk;
      } else {
        u16* dst = (sec == 0) ? Qb : Kb;
        const float scl = (sec == 0) ? 0.125f * 1.44269504f : 1.0f;
#pragma unroll
        for (int r = 0; r < 4; ++r)
          dst[(size_t)((bb * 12 + h) * 2048 + trow + r) * 64 + d] = f2bf((acc[i][j][r] + bv) * scl);
      }
    }
  }
}

// ---------------- proj GEMM: [8192x768] x [768x768], fp32 out + bias ----------------
__global__ __launch_bounds__(256) void gemm_proj_kernel(
    const u16* __restrict__ A, const u16* __restrict__ BT, const float* __restrict__ bias,
    float* __restrict__ out) {
  const int m0 = blockIdx.y * 128, n0 = blockIdx.x * 128;
  GEMM128_MAINLOOP(A, BT, m0, n0)
#pragma unroll
  for (int j = 0; j < 4; ++j) {
    const int n = n0 + nw + j * 16 + l15;
    const float bv = bias[n];
#pragma unroll
    for (int i = 0; i < 4; ++i) {
      const int m = m0 + mw + i * 16 + quad * 4;
#pragma unroll
      for (int r = 0; r < 4; ++r) out[(size_t)(m + r) * 768 + n] = acc[i][j][r] + bv;
    }
  }
}

// ---------------- causal flash attention, MFMA bf16, fixed-max exp2 softmax ----------------
// 128 q-rows/block (two 16-row groups/wave). Scores s' = q·k·0.125·log2e; p = 2^(s'-M).
// No online max (static bound M=20); no per-iter cross-lane ops; packed bf16 converts.
// O^T = V^T·P^T (operand-swapped MFMA) -> shfl-free normalization + vectorized stores.
__global__ __launch_bounds__(256) void attn_kernel(
    const u16* __restrict__ Qg, const u16* __restrict__ Kg, const u16* __restrict__ Vtg,
    u16* __restrict__ Yb) {
  constexpr int T = 2048, D = 64;
  constexpr int LDP = 72;
  constexpr float MBOUND = 20.0f;
  __shared__ u16 Ks[64 * LDP];      // K tile  [k][d]
  __shared__ u16 VTs[64 * LDP];     // V^T tile [d][k]
  __shared__ u16 Ps[4 * 32 * LDP];  // P per-wave, 2 groups x [16 q][64 k]
  const int qb = 15 - blockIdx.x;   // descending work (LPT)
  const int bh = blockIdx.y;
  const int Q0 = qb * 128;
  const int bidx = bh / 12, hidx = bh % 12;
  const int tid = threadIdx.x;
  const int w = tid >> 6, lane = tid & 63;
  const int l15 = lane & 15, quad = lane >> 4;
  const int srow = tid >> 2, scol = (tid & 3) * 16;
  const u16* Kp = Kg + (size_t)bh * T * D;
  const u16* VTp = Vtg + (size_t)bh * D * T;
  u16* pw0 = &Ps[(w * 32) * LDP];
  u16* pw1 = &Ps[(w * 32 + 16) * LDP];

  // Q fragments (B-operand for S^T = K·Q^T), two 16-row groups
  const u16* qrow0 = Qg + ((size_t)bh * T + Q0 + w * 16 + l15) * D;
  const bf16x8 qf0a = *(const bf16x8*)(qrow0 + quad * 8);
  const bf16x8 qf0b = *(const bf16x8*)(qrow0 + 32 + quad * 8);
  const bf16x8 qf1a = *(const bf16x8*)(qrow0 + (size_t)64 * D + quad * 8);
  const bf16x8 qf1b = *(const bf16x8*)(qrow0 + (size_t)64 * D + 32 + quad * 8);
  const int qq0 = Q0 + w * 16 + l15, qq1 = qq0 + 64;

  f32x4 o0[4] = {{0,0,0,0},{0,0,0,0},{0,0,0,0},{0,0,0,0}};  // O^T: row=d, col=q=l15
  f32x4 o1[4] = {{0,0,0,0},{0,0,0,0},{0,0,0,0},{0,0,0,0}};
  float l0v = 0.f, l1v = 0.f;  // per-lane partial denominators

  const int nkt = 2 * qb + 2;
  // prefetch tile 0 into registers
  u32x4 kA = *(const u32x4*)(Kp + (size_t)srow * D + scol);
  u32x4 kB = *(const u32x4*)(Kp + (size_t)srow * D + scol + 8);
  u32x4 vA = *(const u32x4*)(VTp + (size_t)srow * T + scol);
  u32x4 vB = *(const u32x4*)(VTp + (size_t)srow * T + scol + 8);

  for (int kt = 0; kt < nkt; ++kt) {
    __syncthreads();  // all waves done with Ks/VTs
    *(u32x4*)&Ks[srow * LDP + scol] = kA;
    *(u32x4*)&Ks[srow * LDP + scol + 8] = kB;
    *(u32x4*)&VTs[srow * LDP + scol] = vA;
    *(u32x4*)&VTs[srow * LDP + scol + 8] = vB;
    __syncthreads();
    if (kt + 1 < nkt) {  // prefetch next tile; latency overlaps compute below
      const int k1 = (kt + 1) * 64;
      kA = *(const u32x4*)(Kp + (size_t)(k1 + srow) * D + scol);
      kB = *(const u32x4*)(Kp + (size_t)(k1 + srow) * D + scol + 8);
      vA = *(const u32x4*)(VTp + (size_t)srow * T + k1 + scol);
      vB = *(const u32x4*)(VTp + (size_t)srow * T + k1 + scol + 8);
    }
    const int k0 = kt * 64;
    const bool g0a = (kt <= 2 * qb);  // group 0 inactive on the final tile

    // S^T = K·Q^T for both q-groups; K-frags shared
    f32x4 s0[4] = {{0,0,0,0},{0,0,0,0},{0,0,0,0},{0,0,0,0}};
    f32x4 s1[4] = {{0,0,0,0},{0,0,0,0},{0,0,0,0},{0,0,0,0}};
#pragma unroll
    for (int t = 0; t < 4; ++t) {
      const bf16x8 kf0 = *(const bf16x8*)&Ks[(t * 16 + l15) * LDP + quad * 8];
      const bf16x8 kf1 = *(const bf16x8*)&Ks[(t * 16 + l15) * LDP + 32 + quad * 8];
      s0[t] = __builtin_amdgcn_mfma_f32_16x16x32_bf16(kf0, qf0a, s0[t], 0, 0, 0);
      s0[t] = __builtin_amdgcn_mfma_f32_16x16x32_bf16(kf1, qf0b, s0[t], 0, 0, 0);
      s1[t] = __builtin_amdgcn_mfma_f32_16x16x32_bf16(kf0, qf1a, s1[t], 0, 0, 0);
      s1[t] = __builtin_amdgcn_mfma_f32_16x16x32_bf16(kf1, qf1b, s1[t], 0, 0, 0);
    }
    // ---- fixed-max softmax, group 0: p = 2^(s-M); no cross-lane ops ----
    if (g0a) {
      if (kt == 2 * qb) {  // diagonal for g0
#pragma unroll
        for (int t = 0; t < 4; ++t)
#pragma unroll
          for (int r = 0; r < 4; ++r)
            if (k0 + t * 16 + quad * 4 + r > qq0) s0[t][r] = -1e30f;
      }
#pragma unroll
      for (int t = 0; t < 4; ++t) {
        float e0 = __builtin_amdgcn_exp2f(s0[t][0] - MBOUND);
        float e1 = __builtin_amdgcn_exp2f(s0[t][1] - MBOUND);
        float e2 = __builtin_amdgcn_exp2f(s0[t][2] - MBOUND);
        float e3 = __builtin_amdgcn_exp2f(s0[t][3] - MBOUND);
        l0v += (e0 + e1) + (e2 + e3);
        u32x2 pk;
        pk[0] = cvtpk(e0, e1);
        pk[1] = cvtpk(e2, e3);
        *(u32x2*)&pw0[l15 * LDP + t * 16 + quad * 4] = pk;
      }
    }
    // ---- group 1 ----
    {
      if (kt == 2 * qb + 1) {  // diagonal for g1
#pragma unroll
        for (int t = 0; t < 4; ++t)
#pragma unroll
          for (int r = 0; r < 4; ++r)
            if (k0 + t * 16 + quad * 4 + r > qq1) s1[t][r] = -1e30f;
      }
#pragma unroll
      for (int t = 0; t < 4; ++t) {
        float e0 = __builtin_amdgcn_exp2f(s1[t][0] - MBOUND);
        float e1 = __builtin_amdgcn_exp2f(s1[t][1] - MBOUND);
        float e2 = __builtin_amdgcn_exp2f(s1[t][2] - MBOUND);
        float e3 = __builtin_amdgcn_exp2f(s1[t][3] - MBOUND);
        l1v += (e0 + e1) + (e2 + e3);
        u32x2 pk;
        pk[0] = cvtpk(e0, e1);
        pk[1] = cvtpk(e2, e3);
        *(u32x2*)&pw1[l15 * LDP + t * 16 + quad * 4] = pk;
      }
    }
    // ---- O^T += V^T·P^T for both groups; V-frags (A-operand) shared ----
    const bf16x8 p0a = *(const bf16x8*)&pw0[l15 * LDP + quad * 8];
    const bf16x8 p0b = *(const bf16x8*)&pw0[l15 * LDP + 32 + quad * 8];
    const bf16x8 p1a = *(const bf16x8*)&pw1[l15 * LDP + quad * 8];
    const bf16x8 p1b = *(const bf16x8*)&pw1[l15 * LDP + 32 + quad * 8];
#pragma unroll
    for (int t = 0; t < 4; ++t) {
      const bf16x8 vf0 = *(const bf16x8*)&VTs[(t * 16 + l15) * LDP + quad * 8];
      const bf16x8 vf1 = *(const bf16x8*)&VTs[(t * 16 + l15) * LDP + 32 + quad * 8];
      if (g0a) {
        o0[t] = __builtin_amdgcn_mfma_f32_16x16x32_bf16(vf0, p0a, o0[t], 0, 0, 0);
        o0[t] = __builtin_amdgcn_mfma_f32_16x16x32_bf16(vf1, p0b, o0[t], 0, 0, 0);
      }
      o1[t] = __builtin_amdgcn_mfma_f32_16x16x32_bf16(vf0, p1a, o1[t], 0, 0, 0);
      o1[t] = __builtin_amdgcn_mfma_f32_16x16x32_bf16(vf1, p1b, o1[t], 0, 0, 0);
    }
  }
  // final l reduction (once): sum the 4 quad partials for this lane's q=l15
  l0v += __shfl_xor(l0v, 16); l0v += __shfl_xor(l0v, 32);
  l1v += __shfl_xor(l1v, 16); l1v += __shfl_xor(l1v, 32);
  const float inv0 = 1.f / l0v, inv1 = 1.f / l1v;
  // epilogue: O^T rows are d=16t+quad*4+r, col q=l15 -> u64 stores along d
  u16* y0 = Yb + ((size_t)bidx * T + qq0) * 768 + hidx * 64;
  u16* y1 = Yb + ((size_t)bidx * T + qq1) * 768 + hidx * 64;
#pragma unroll
  for (int t = 0; t < 4; ++t) {
    u32x2 pk0, pk1;
    pk0[0] = cvtpk(o0[t][0] * inv0, o0[t][1] * inv0);
    pk0[1] = cvtpk(o0[t][2] * inv0, o0[t][3] * inv0);
    pk1[0] = cvtpk(o1[t][0] * inv1, o1[t][1] * inv1);
    pk1[1] = cvtpk(o1[t][2] * inv1, o1[t][3] * inv1);
    *(u32x2*)(y0 + t * 16 + quad * 4) = pk0;
    *(u32x2*)(y1 + t * 16 + quad * 4) = pk1;
  }
}

extern "C" void kernel_launch(void* const* d_in, const int* in_sizes, int n_in,
                              void* d_out, int out_size, void* d_ws, size_t ws_size,
                              hipStream_t stream) {
  const float* x = (const float*)d_in[0];
  const float* W_qkv = (const float*)d_in[1];
  const float* b_qkv = (const float*)d_in[2];
  const float* W_proj = (const float*)d_in[3];
  const float* b_proj = (const float*)d_in[4];
  float* out = (float*)d_out;

  constexpr size_t MC = (size_t)8192 * 768;
  u16* xb = (u16*)d_ws;
  u16* Qb = xb + MC;
  u16* Kb = Qb + MC;
  u16* Vt = Kb + MC;   // transposed V: [bh][d][t]
  u16* Yb = Vt + MC;
  u16* WqkvT = Yb + MC;
  u16* WprojT = WqkvT + (size_t)2304 * 768;

  cast_x_kernel<<<6291456 / (4 * 256), 256, 0, stream>>>(x, xb, 6291456 / 4);
  transpose_cast_kernel<<<dim3(2304 / 32, 768 / 32), 256, 0, stream>>>(W_qkv, WqkvT, 768, 2304);
  transpose_cast_kernel<<<dim3(768 / 32, 768 / 32), 256, 0, stream>>>(W_proj, WprojT, 768, 768);
  gemm_qkv_kernel<<<dim3(18, 64), 256, 0, stream>>>(xb, WqkvT, b_qkv, Qb, Kb, Vt);
  attn_kernel<<<dim3(16, 48), 256, 0, stream>>>(Qb, Kb, Vt, Yb);
  gemm_proj_kernel<<<dim3(6, 64), 256, 0, stream>>>(Yb, WprojT, b_proj, out);
}

// Round 8
// 244.865 us; speedup vs baseline: 3.7040x; 1.0700x over previous
//
#include <hip/hip_runtime.h>
#include <hip/hip_bf16.h>

typedef __bf16 bf16x8 __attribute__((ext_vector_type(8)));
typedef float f32x4 __attribute__((ext_vector_type(4)));
typedef unsigned int u32x4 __attribute__((ext_vector_type(4)));
typedef unsigned int u32x2 __attribute__((ext_vector_type(2)));
typedef unsigned short u16;
typedef unsigned long long u64;

__device__ __forceinline__ u16 f2bf(float f) {
  unsigned u = __builtin_bit_cast(unsigned, f);
  u += 0x7FFFu + ((u >> 16) & 1u);   // RNE
  return (u16)(u >> 16);
}
// HW packed convert: 2 fp32 -> 2 bf16 (v_cvt_pk_bf16_f32, RNE)
__device__ __forceinline__ unsigned cvtpk(float a, float b) {
  float2 f; f.x = a; f.y = b;
  __hip_bfloat162 h = __float22bfloat162_rn(f);
  unsigned u;
  __builtin_memcpy(&u, &h, 4);
  return u;
}

// async global->LDS direct copy, 16B per lane. LDS dest = wave-uniform base + lane*16.
__device__ __forceinline__ void gll16(const u16* g, u16* l) {
  __builtin_amdgcn_global_load_lds(
      (const __attribute__((address_space(1))) unsigned int*)g,
      (__attribute__((address_space(3))) unsigned int*)l, 16, 0, 0);
}

// ---------------- cast x (fp32 -> bf16), vectorized ----------------
__global__ void cast_x_kernel(const float* __restrict__ in, u16* __restrict__ out, int n4) {
  int i = blockIdx.x * blockDim.x + threadIdx.x;
  if (i >= n4) return;
  f32x4 v = *(const f32x4*)(in + (size_t)i * 4);
  u32x2 pk;
  pk[0] = cvtpk(v[0], v[1]);
  pk[1] = cvtpk(v[2], v[3]);
  *(u32x2*)(out + (size_t)i * 4) = pk;
}

// ------------- transpose + cast: W[K][N] fp32 -> WT[N][K] bf16 -------------
__global__ void transpose_cast_kernel(const float* __restrict__ W, u16* __restrict__ WT, int K, int N) {
  __shared__ float tile[32][33];
  int c0 = blockIdx.x * 32, r0 = blockIdx.y * 32;
  int tx = threadIdx.x & 31, tg = threadIdx.x >> 5;
#pragma unroll
  for (int i = 0; i < 4; ++i) {
    int r = tg + i * 8;
    tile[r][tx] = W[(size_t)(r0 + r) * N + c0 + tx];
  }
  __syncthreads();
#pragma unroll
  for (int i = 0; i < 4; ++i) {
    int r = tg + i * 8;
    WT[(size_t)(c0 + r) * K + r0 + tx] = f2bf(tile[tx][r]);
  }
}

// ======== shared 128x128 MFMA mainloop (m97-style: BK=32, global_load_lds) ========
#define GEMM128_MAINLOOP(A, BT, m0, n0)                                                     \
  constexpr int K = 768;                                                                    \
  __shared__ u16 Asm[128 * 32];                                                             \
  __shared__ u16 Bsm[128 * 32];                                                             \
  const int tid = threadIdx.x;                                                              \
  const int w = tid >> 6, lane = tid & 63;                                                  \
  const int l15 = lane & 15, quad = lane >> 4;                                              \
  const int srow = tid >> 2, scol = (tid & 3) * 8;                                          \
  const u16* Ag0 = (A) + (size_t)((m0) + srow) * K + scol;                                  \
  const u16* Ag1 = (A) + (size_t)((m0) + 64 + srow) * K + scol;                             \
  const u16* Bg0 = (BT) + (size_t)((n0) + srow) * K + scol;                                 \
  const u16* Bg1 = (BT) + (size_t)((n0) + 64 + srow) * K + scol;                            \
  u16* Al0 = &Asm[(w * 64) * 8];                                                            \
  u16* Al1 = &Asm[(256 + w * 64) * 8];                                                      \
  u16* Bl0 = &Bsm[(w * 64) * 8];                                                            \
  u16* Bl1 = &Bsm[(256 + w * 64) * 8];                                                      \
  const int mw = (w >> 1) * 64, nw = (w & 1) * 64;                                          \
  f32x4 acc[4][4];                                                                          \
  _Pragma("unroll") for (int i = 0; i < 4; ++i) _Pragma("unroll") for (int j = 0; j < 4;    \
                                                                       ++j) acc[i][j] = {   \
      0.f, 0.f, 0.f, 0.f};                                                                  \
  for (int k0 = 0; k0 < K; k0 += 32) {                                                      \
    __syncthreads();                                                                        \
    gll16(Ag0 + k0, Al0);                                                                   \
    gll16(Ag1 + k0, Al1);                                                                   \
    gll16(Bg0 + k0, Bl0);                                                                   \
    gll16(Bg1 + k0, Bl1);                                                                   \
    __syncthreads();                                                                        \
    bf16x8 af[4], bfj[4];                                                                   \
    _Pragma("unroll") for (int i = 0; i < 4; ++i) af[i] =                                   \
        *(const bf16x8*)&Asm[(mw + i * 16 + l15) * 32 + quad * 8];                          \
    _Pragma("unroll") for (int j = 0; j < 4; ++j) bfj[j] =                                  \
        *(const bf16x8*)&Bsm[(nw + j * 16 + l15) * 32 + quad * 8];                          \
    _Pragma("unroll") for (int i = 0; i < 4; ++i) _Pragma("unroll") for (int j = 0; j < 4;  \
                                                                         ++j) acc[i][j] =  \
        __builtin_amdgcn_mfma_f32_16x16x32_bf16(af[i], bfj[j], acc[i][j], 0, 0, 0);         \
  }

// ---------------- QKV GEMM: [8192x768] x [768x2304] ----------------
// Q pre-scaled by 0.125*log2(e) (exp2-domain attention). V written TRANSPOSED: Vt[bh][d][t].
__global__ __launch_bounds__(256) void gemm_qkv_kernel(
    const u16* __restrict__ A, const u16* __restrict__ BT, const float* __restrict__ bias,
    u16* __restrict__ Qb, u16* __restrict__ Kb, u16* __restrict__ Vt) {
  const int m0 = blockIdx.y * 128, n0 = blockIdx.x * 128;
  GEMM128_MAINLOOP(A, BT, m0, n0)
  const int sec = blockIdx.x / 6;           // 0:Q 1:K 2:V (uniform per block; 768%128==0)
  const int nbase = n0 - sec * 768;
#pragma unroll
  for (int j = 0; j < 4; ++j) {
    const int nloc = nbase + nw + j * 16 + l15;
    const float bv = bias[sec * 768 + nloc];
    const int h = nloc >> 6, d = nloc & 63;
#pragma unroll
    for (int i = 0; i < 4; ++i) {
      const int m = m0 + mw + i * 16 + quad * 4;
      const int bb = m >> 11, trow = m & 2047;
      if (sec == 2) {
        u32x2 pk;
        pk[0] = cvtpk(acc[i][j][0] + bv, acc[i][j][1] + bv);
        pk[1] = cvtpk(acc[i][j][2] + bv, acc[i][j][3] + bv);
        *(u32x2*)(Vt + (size_t)((bb * 12 + h) * 64 + d) * 2048 + trow) = pk;
      } else {
        u16* dst = (sec == 0) ? Qb : Kb;
        const float scl = (sec == 0) ? 0.125f * 1.44269504f : 1.0f;
#pragma unroll
        for (int r = 0; r < 4; ++r)
          dst[(size_t)((bb * 12 + h) * 2048 + trow + r) * 64 + d] = f2bf((acc[i][j][r] + bv) * scl);
      }
    }
  }
}

// ---------------- proj GEMM: 64x128 tiles (768 blocks = 3/CU), fp32 out + bias ----------------
__global__ __launch_bounds__(256) void gemm_proj_kernel(
    const u16* __restrict__ A, const u16* __restrict__ BT, const float* __restrict__ bias,
    float* __restrict__ out) {
  constexpr int K = 768;
  __shared__ u16 Asm[64 * 32];
  __shared__ u16 Bsm[128 * 32];
  const int tid = threadIdx.x;
  const int w = tid >> 6, lane = tid & 63;
  const int l15 = lane & 15, quad = lane >> 4;
  const int srow = tid >> 2, scol = (tid & 3) * 8;
  const int m0 = blockIdx.y * 64, n0 = blockIdx.x * 128;
  const u16* Ag = A + (size_t)(m0 + srow) * K + scol;
  const u16* Bg0 = BT + (size_t)(n0 + srow) * K + scol;
  const u16* Bg1 = BT + (size_t)(n0 + 64 + srow) * K + scol;
  u16* Al = &Asm[(w * 64) * 8];
  u16* Bl0 = &Bsm[(w * 64) * 8];
  u16* Bl1 = &Bsm[(256 + w * 64) * 8];
  const int mw = (w >> 1) * 32, nw = (w & 1) * 64;
  f32x4 acc[2][4];
#pragma unroll
  for (int i = 0; i < 2; ++i)
#pragma unroll
    for (int j = 0; j < 4; ++j) acc[i][j] = {0.f, 0.f, 0.f, 0.f};
  for (int k0 = 0; k0 < K; k0 += 32) {
    __syncthreads();
    gll16(Ag + k0, Al);
    gll16(Bg0 + k0, Bl0);
    gll16(Bg1 + k0, Bl1);
    __syncthreads();
    bf16x8 af[2], bfj[4];
#pragma unroll
    for (int i = 0; i < 2; ++i) af[i] = *(const bf16x8*)&Asm[(mw + i * 16 + l15) * 32 + quad * 8];
#pragma unroll
    for (int j = 0; j < 4; ++j) bfj[j] = *(const bf16x8*)&Bsm[(nw + j * 16 + l15) * 32 + quad * 8];
#pragma unroll
    for (int i = 0; i < 2; ++i)
#pragma unroll
      for (int j = 0; j < 4; ++j)
        acc[i][j] = __builtin_amdgcn_mfma_f32_16x16x32_bf16(af[i], bfj[j], acc[i][j], 0, 0, 0);
  }
#pragma unroll
  for (int j = 0; j < 4; ++j) {
    const int n = n0 + nw + j * 16 + l15;
    const float bv = bias[n];
#pragma unroll
    for (int i = 0; i < 2; ++i) {
      const int m = m0 + mw + i * 16 + quad * 4;
#pragma unroll
      for (int r = 0; r < 4; ++r) out[(size_t)(m + r) * 768 + n] = acc[i][j][r] + bv;
    }
  }
}

// ---------------- split-K causal flash attention (fixed-max exp2 softmax) ----------------
// Work unit: (bh, 64-q tile qt, chunk of <=8 k-tiles). 80 slots per bh.
// slot decode: qt 0..7 -> 1 chunk; 8..15 -> 2; 16..23 -> 3; 24..31 -> 4.
// Single-chunk (qt<=7): write Yb directly. Else: write unnormalized fp32 O[q][d] + l partials.
__global__ __launch_bounds__(256) void attn_split_kernel(
    const u16* __restrict__ Qg, const u16* __restrict__ Kg, const u16* __restrict__ Vtg,
    u16* __restrict__ Yb, float* __restrict__ Opart, float* __restrict__ lpart) {
  constexpr int T = 2048, D = 64;
  constexpr int LDP = 72;
  constexpr float MBOUND = 20.0f;
  __shared__ u16 Ks[64 * LDP];      // K tile  [k][d]
  __shared__ u16 VTs[64 * LDP];     // V^T tile [d][k]
  __shared__ u16 Ps[4 * 16 * LDP];  // P per-wave [16 q][64 k]
  const int s = 79 - blockIdx.x;    // long chunks first
  const int bh = blockIdx.y;
  int qt, c;
  if (s < 8) { qt = s; c = 0; }
  else if (s < 24) { qt = 8 + ((s - 8) >> 1); c = (s - 8) & 1; }
  else if (s < 48) { int u = s - 24; int q3 = u / 3; qt = 16 + q3; c = u - 3 * q3; }
  else { int u = s - 48; qt = 24 + (u >> 2); c = u & 3; }
  const int niter = min(8, qt + 1 - 8 * c);
  const int tid = threadIdx.x;
  const int w = tid >> 6, lane = tid & 63;
  const int l15 = lane & 15, quad = lane >> 4;
  const int srow = tid >> 2, scol = (tid & 3) * 16;
  const u16* Kp = Kg + (size_t)bh * T * D;
  const u16* VTp = Vtg + (size_t)bh * D * T;
  u16* pw = &Ps[(w * 16) * LDP];

  // Q fragments (B-operand for S^T = K.Q^T): this wave's 16 q rows
  const int qq = qt * 64 + w * 16 + l15;
  const u16* qrow = Qg + ((size_t)bh * T + qq) * D;
  const bf16x8 qfa = *(const bf16x8*)(qrow + quad * 8);
  const bf16x8 qfb = *(const bf16x8*)(qrow + 32 + quad * 8);

  f32x4 o[4] = {{0,0,0,0},{0,0,0,0},{0,0,0,0},{0,0,0,0}};  // O^T: row=d, col=q=l15
  float lv = 0.f;

  // prefetch first tile of the chunk
  int ktg = c * 8;
  u32x4 kA = *(const u32x4*)(Kp + (size_t)(ktg * 64 + srow) * D + scol);
  u32x4 kB = *(const u32x4*)(Kp + (size_t)(ktg * 64 + srow) * D + scol + 8);
  u32x4 vA = *(const u32x4*)(VTp + (size_t)srow * T + ktg * 64 + scol);
  u32x4 vB = *(const u32x4*)(VTp + (size_t)srow * T + ktg * 64 + scol + 8);

  for (int j = 0; j < niter; ++j) {
    ktg = c * 8 + j;
    __syncthreads();
    *(u32x4*)&Ks[srow * LDP + scol] = kA;
    *(u32x4*)&Ks[srow * LDP + scol + 8] = kB;
    *(u32x4*)&VTs[srow * LDP + scol] = vA;
    *(u32x4*)&VTs[srow * LDP + scol + 8] = vB;
    __syncthreads();
    if (j + 1 < niter) {
      const int k1 = (ktg + 1) * 64;
      kA = *(const u32x4*)(Kp + (size_t)(k1 + srow) * D + scol);
      kB = *(const u32x4*)(Kp + (size_t)(k1 + srow) * D + scol + 8);
      vA = *(const u32x4*)(VTp + (size_t)srow * T + k1 + scol);
      vB = *(const u32x4*)(VTp + (size_t)srow * T + k1 + scol + 8);
    }
    // S^T = K.Q^T : C-layout row = k_local = 16t+quad*4+r, col = q = l15
    f32x4 sA[4] = {{0,0,0,0},{0,0,0,0},{0,0,0,0},{0,0,0,0}};
#pragma unroll
    for (int t = 0; t < 4; ++t) {
      const bf16x8 kf0 = *(const bf16x8*)&Ks[(t * 16 + l15) * LDP + quad * 8];
      const bf16x8 kf1 = *(const bf16x8*)&Ks[(t * 16 + l15) * LDP + 32 + quad * 8];
      sA[t] = __builtin_amdgcn_mfma_f32_16x16x32_bf16(kf0, qfa, sA[t], 0, 0, 0);
      sA[t] = __builtin_amdgcn_mfma_f32_16x16x32_bf16(kf1, qfb, sA[t], 0, 0, 0);
    }
    if (ktg == qt) {  // diagonal tile: causal mask
      const int k0 = ktg * 64;
#pragma unroll
      for (int t = 0; t < 4; ++t)
#pragma unroll
        for (int r = 0; r < 4; ++r)
          if (k0 + t * 16 + quad * 4 + r > qq) sA[t][r] = -1e30f;
    }
    // fixed-max softmax: p = 2^(s-M), no cross-lane ops
#pragma unroll
    for (int t = 0; t < 4; ++t) {
      float e0 = __builtin_amdgcn_exp2f(sA[t][0] - MBOUND);
      float e1 = __builtin_amdgcn_exp2f(sA[t][1] - MBOUND);
      float e2 = __builtin_amdgcn_exp2f(sA[t][2] - MBOUND);
      float e3 = __builtin_amdgcn_exp2f(sA[t][3] - MBOUND);
      lv += (e0 + e1) + (e2 + e3);
      u32x2 pk;
      pk[0] = cvtpk(e0, e1);
      pk[1] = cvtpk(e2, e3);
      *(u32x2*)&pw[l15 * LDP + t * 16 + quad * 4] = pk;
    }
    // O^T += V^T.P^T
    const bf16x8 pa = *(const bf16x8*)&pw[l15 * LDP + quad * 8];
    const bf16x8 pb = *(const bf16x8*)&pw[l15 * LDP + 32 + quad * 8];
#pragma unroll
    for (int t = 0; t < 4; ++t) {
      const bf16x8 vf0 = *(const bf16x8*)&VTs[(t * 16 + l15) * LDP + quad * 8];
      const bf16x8 vf1 = *(const bf16x8*)&VTs[(t * 16 + l15) * LDP + 32 + quad * 8];
      o[t] = __builtin_amdgcn_mfma_f32_16x16x32_bf16(vf0, pa, o[t], 0, 0, 0);
      o[t] = __builtin_amdgcn_mfma_f32_16x16x32_bf16(vf1, pb, o[t], 0, 0, 0);
    }
  }
  // reduce l across quads (all lanes get total for their q=l15)
  lv += __shfl_xor(lv, 16);
  lv += __shfl_xor(lv, 32);
  if (qt <= 7) {
    // single chunk: normalize + write Yb directly
    const float inv = 1.f / lv;
    const int bidx = bh / 12, hidx = bh % 12;
    u16* y = Yb + ((size_t)bidx * T + qq) * 768 + hidx * 64;
#pragma unroll
    for (int t = 0; t < 4; ++t) {
      u32x2 pk;
      pk[0] = cvtpk(o[t][0] * inv, o[t][1] * inv);
      pk[1] = cvtpk(o[t][2] * inv, o[t][3] * inv);
      *(u32x2*)(y + t * 16 + quad * 4) = pk;
    }
  } else {
    // write unnormalized partials: Opart[pidx][q(64)][d(64)] fp32, lpart[pidx][q]
    const size_t pidx = (size_t)bh * 80 + s;
    float* Op = Opart + pidx * 4096 + (size_t)(w * 16 + l15) * 64;
#pragma unroll
    for (int t = 0; t < 4; ++t) *(f32x4*)(Op + t * 16 + quad * 4) = o[t];
    if (quad == 0) lpart[pidx * 64 + w * 16 + l15] = lv;
  }
}

// ---------------- combine partials for qt >= 8 ----------------
__global__ __launch_bounds__(256) void attn_combine_kernel(
    const float* __restrict__ Opart, const float* __restrict__ lpart, u16* __restrict__ Yb) {
  constexpr int T = 2048;
  const int qt = 8 + blockIdx.x;
  const int bh = blockIdx.y;
  const int nch = (qt < 16) ? 2 : (qt < 24) ? 3 : 4;
  const int off = (qt < 16) ? 8 + (qt - 8) * 2 : (qt < 24) ? 24 + (qt - 16) * 3 : 48 + (qt - 24) * 4;
  const size_t base = (size_t)bh * 80 + off;
  const int tid = threadIdx.x;
  const int q = tid >> 2, db = (tid & 3) * 16;
  f32x4 o[4] = {{0,0,0,0},{0,0,0,0},{0,0,0,0},{0,0,0,0}};
  float l = 0.f;
  for (int cc = 0; cc < nch; ++cc) {
    const float* Op = Opart + (base + cc) * 4096 + (size_t)q * 64 + db;
#pragma unroll
    for (int v = 0; v < 4; ++v) o[v] += *(const f32x4*)(Op + v * 4);
    l += lpart[(base + cc) * 64 + q];
  }
  const float inv = 1.f / l;
  const int bidx = bh / 12, hidx = bh % 12;
  u16* y = Yb + ((size_t)bidx * T + qt * 64 + q) * 768 + hidx * 64 + db;
  u32x4 pk;
  pk[0] = cvtpk(o[0][0] * inv, o[0][1] * inv);
  pk[1] = cvtpk(o[0][2] * inv, o[0][3] * inv);
  pk[2] = cvtpk(o[1][0] * inv, o[1][1] * inv);
  pk[3] = cvtpk(o[1][2] * inv, o[1][3] * inv);
  *(u32x4*)y = pk;
  pk[0] = cvtpk(o[2][0] * inv, o[2][1] * inv);
  pk[1] = cvtpk(o[2][2] * inv, o[2][3] * inv);
  pk[2] = cvtpk(o[3][0] * inv, o[3][1] * inv);
  pk[3] = cvtpk(o[3][2] * inv, o[3][3] * inv);
  *(u32x4*)(y + 8) = pk;
}

// ---------------- fallback: round-7 attention (used if ws too small) ----------------
__global__ __launch_bounds__(256) void attn_kernel(
    const u16* __restrict__ Qg, const u16* __restrict__ Kg, const u16* __restrict__ Vtg,
    u16* __restrict__ Yb) {
  constexpr int T = 2048, D = 64;
  constexpr int LDP = 72;
  constexpr float MBOUND = 20.0f;
  __shared__ u16 Ks[64 * LDP];
  __shared__ u16 VTs[64 * LDP];
  __shared__ u16 Ps[4 * 32 * LDP];
  const int qb = 15 - blockIdx.x;
  const int bh = blockIdx.y;
  const int Q0 = qb * 128;
  const int bidx = bh / 12, hidx = bh % 12;
  const int tid = threadIdx.x;
  const int w = tid >> 6, lane = tid & 63;
  const int l15 = lane & 15, quad = lane >> 4;
  const int srow = tid >> 2, scol = (tid & 3) * 16;
  const u16* Kp = Kg + (size_t)bh * T * D;
  const u16* VTp = Vtg + (size_t)bh * D * T;
  u16* pw0 = &Ps[(w * 32) * LDP];
  u16* pw1 = &Ps[(w * 32 + 16) * LDP];
  const u16* qrow0 = Qg + ((size_t)bh * T + Q0 + w * 16 + l15) * D;
  const bf16x8 qf0a = *(const bf16x8*)(qrow0 + quad * 8);
  const bf16x8 qf0b = *(const bf16x8*)(qrow0 + 32 + quad * 8);
  const bf16x8 qf1a = *(const bf16x8*)(qrow0 + (size_t)64 * D + quad * 8);
  const bf16x8 qf1b = *(const bf16x8*)(qrow0 + (size_t)64 * D + 32 + quad * 8);
  const int qq0 = Q0 + w * 16 + l15, qq1 = qq0 + 64;
  f32x4 o0[4] = {{0,0,0,0},{0,0,0,0},{0,0,0,0},{0,0,0,0}};
  f32x4 o1[4] = {{0,0,0,0},{0,0,0,0},{0,0,0,0},{0,0,0,0}};
  float l0v = 0.f, l1v = 0.f;
  const int nkt = 2 * qb + 2;
  u32x4 kA = *(const u32x4*)(Kp + (size_t)srow * D + scol);
  u32x4 kB = *(const u32x4*)(Kp + (size_t)srow * D + scol + 8);
  u32x4 vA = *(const u32x4*)(VTp + (size_t)srow * T + scol);
  u32x4 vB = *(const u32x4*)(VTp + (size_t)srow * T + scol + 8);
  for (int kt = 0; kt < nkt; ++kt) {
    __syncthreads();
    *(u32x4*)&Ks[srow * LDP + scol] = kA;
    *(u32x4*)&Ks[srow * LDP + scol + 8] = kB;
    *(u32x4*)&VTs[srow * LDP + scol] = vA;
    *(u32x4*)&VTs[srow * LDP + scol + 8] = vB;
    __syncthreads();
    if (kt + 1 < nkt) {
      const int k1 = (kt + 1) * 64;
      kA = *(const u32x4*)(Kp + (size_t)(k1 + srow) * D + scol);
      kB = *(const u32x4*)(Kp + (size_t)(k1 + srow) * D + scol + 8);
      vA = *(const u32x4*)(VTp + (size_t)srow * T + k1 + scol);
      vB = *(const u32x4*)(VTp + (size_t)srow * T + k1 + scol + 8);
    }
    const int k0 = kt * 64;
    const bool g0a = (kt <= 2 * qb);
    f32x4 s0[4] = {{0,0,0,0},{0,0,0,0},{0,0,0,0},{0,0,0,0}};
    f32x4 s1[4] = {{0,0,0,0},{0,0,0,0},{0,0,0,0},{0,0,0,0}};
#pragma unroll
    for (int t = 0; t < 4; ++t) {
      const bf16x8 kf0 = *(const bf16x8*)&Ks[(t * 16 + l15) * LDP + quad * 8];
      const bf16x8 kf1 = *(const bf16x8*)&Ks[(t * 16 + l15) * LDP + 32 + quad * 8];
      s0[t] = __builtin_amdgcn_mfma_f32_16x16x32_bf16(kf0, qf0a, s0[t], 0, 0, 0);
      s0[t] = __builtin_amdgcn_mfma_f32_16x16x32_bf16(kf1, qf0b, s0[t], 0, 0, 0);
      s1[t] = __builtin_amdgcn_mfma_f32_16x16x32_bf16(kf0, qf1a, s1[t], 0, 0, 0);
      s1[t] = __builtin_amdgcn_mfma_f32_16x16x32_bf16(kf1, qf1b, s1[t], 0, 0, 0);
    }
    if (g0a) {
      if (kt == 2 * qb) {
#pragma unroll
        for (int t = 0; t < 4; ++t)
#pragma unroll
          for (int r = 0; r < 4; ++r)
            if (k0 + t * 16 + quad * 4 + r > qq0) s0[t][r] = -1e30f;
      }
#pragma unroll
      for (int t = 0; t < 4; ++t) {
        float e0 = __builtin_amdgcn_exp2f(s0[t][0] - MBOUND);
        float e1 = __builtin_amdgcn_exp2f(s0[t][1] - MBOUND);
        float e2 = __builtin_amdgcn_exp2f(s0[t][2] - MBOUND);
        float e3 = __builtin_amdgcn_exp2f(s0[t][3] - MBOUND);
        l0v += (e0 + e1) + (e2 + e3);
        u32x2 pk;
        pk[0] = cvtpk(e0, e1);
        pk[1] = cvtpk(e2, e3);
        *(u32x2*)&pw0[l15 * LDP + t * 16 + quad * 4] = pk;
      }
    }
    {
      if (kt == 2 * qb + 1) {
#pragma unroll
        for (int t = 0; t < 4; ++t)
#pragma unroll
          for (int r = 0; r < 4; ++r)
            if (k0 + t * 16 + quad * 4 + r > qq1) s1[t][r] = -1e30f;
      }
#pragma unroll
      for (int t = 0; t < 4; ++t) {
        float e0 = __builtin_amdgcn_exp2f(s1[t][0] - MBOUND);
        float e1 = __builtin_amdgcn_exp2f(s1[t][1] - MBOUND);
        float e2 = __builtin_amdgcn_exp2f(s1[t][2] - MBOUND);
        float e3 = __builtin_amdgcn_exp2f(s1[t][3] - MBOUND);
        l1v += (e0 + e1) + (e2 + e3);
        u32x2 pk;
        pk[0] = cvtpk(e0, e1);
        pk[1] = cvtpk(e2, e3);
        *(u32x2*)&pw1[l15 * LDP + t * 16 + quad * 4] = pk;
      }
    }
    const bf16x8 p0a = *(const bf16x8*)&pw0[l15 * LDP + quad * 8];
    const bf16x8 p0b = *(const bf16x8*)&pw0[l15 * LDP + 32 + quad * 8];
    const bf16x8 p1a = *(const bf16x8*)&pw1[l15 * LDP + quad * 8];
    const bf16x8 p1b = *(const bf16x8*)&pw1[l15 * LDP + 32 + quad * 8];
#pragma unroll
    for (int t = 0; t < 4; ++t) {
      const bf16x8 vf0 = *(const bf16x8*)&VTs[(t * 16 + l15) * LDP + quad * 8];
      const bf16x8 vf1 = *(const bf16x8*)&VTs[(t * 16 + l15) * LDP + 32 + quad * 8];
      if (g0a) {
        o0[t] = __builtin_amdgcn_mfma_f32_16x16x32_bf16(vf0, p0a, o0[t], 0, 0, 0);
        o0[t] = __builtin_amdgcn_mfma_f32_16x16x32_bf16(vf1, p0b, o0[t], 0, 0, 0);
      }
      o1[t] = __builtin_amdgcn_mfma_f32_16x16x32_bf16(vf0, p1a, o1[t], 0, 0, 0);
      o1[t] = __builtin_amdgcn_mfma_f32_16x16x32_bf16(vf1, p1b, o1[t], 0, 0, 0);
    }
  }
  l0v += __shfl_xor(l0v, 16); l0v += __shfl_xor(l0v, 32);
  l1v += __shfl_xor(l1v, 16); l1v += __shfl_xor(l1v, 32);
  const float inv0 = 1.f / l0v, inv1 = 1.f / l1v;
  u16* y0 = Yb + ((size_t)bidx * T + qq0) * 768 + hidx * 64;
  u16* y1 = Yb + ((size_t)bidx * T + qq1) * 768 + hidx * 64;
#pragma unroll
  for (int t = 0; t < 4; ++t) {
    u32x2 pk0, pk1;
    pk0[0] = cvtpk(o0[t][0] * inv0, o0[t][1] * inv0);
    pk0[1] = cvtpk(o0[t][2] * inv0, o0[t][3] * inv0);
    pk1[0] = cvtpk(o1[t][0] * inv1, o1[t][1] * inv1);
    pk1[1] = cvtpk(o1[t][2] * inv1, o1[t][3] * inv1);
    *(u32x2*)(y0 + t * 16 + quad * 4) = pk0;
    *(u32x2*)(y1 + t * 16 + quad * 4) = pk1;
  }
}

extern "C" void kernel_launch(void* const* d_in, const int* in_sizes, int n_in,
                              void* d_out, int out_size, void* d_ws, size_t ws_size,
                              hipStream_t stream) {
  const float* x = (const float*)d_in[0];
  const float* W_qkv = (const float*)d_in[1];
  const float* b_qkv = (const float*)d_in[2];
  const float* W_proj = (const float*)d_in[3];
  const float* b_proj = (const float*)d_in[4];
  float* out = (float*)d_out;

  constexpr size_t MC = (size_t)8192 * 768;
  u16* xb = (u16*)d_ws;
  u16* Qb = xb + MC;
  u16* Kb = Qb + MC;
  u16* Vt = Kb + MC;   // transposed V: [bh][d][t]
  u16* Yb = Vt + MC;
  u16* WqkvT = Yb + MC;
  u16* WprojT = WqkvT + (size_t)2304 * 768;
  // split-K partials (after the bf16 region)
  constexpr size_t BASE_U16 = 5 * MC + (size_t)2304 * 768 + (size_t)768 * 768;  // 33,816,576
  float* Opart = (float*)((u16*)d_ws + BASE_U16);
  float* lpart = Opart + (size_t)3840 * 4096;
  constexpr size_t NEED = BASE_U16 * 2 + ((size_t)3840 * 4096 + (size_t)3840 * 64) * 4;
  const bool use_split = (ws_size >= NEED);

  cast_x_kernel<<<6291456 / (4 * 256), 256, 0, stream>>>(x, xb, 6291456 / 4);
  transpose_cast_kernel<<<dim3(2304 / 32, 768 / 32), 256, 0, stream>>>(W_qkv, WqkvT, 768, 2304);
  transpose_cast_kernel<<<dim3(768 / 32, 768 / 32), 256, 0, stream>>>(W_proj, WprojT, 768, 768);
  gemm_qkv_kernel<<<dim3(18, 64), 256, 0, stream>>>(xb, WqkvT, b_qkv, Qb, Kb, Vt);
  if (use_split) {
    attn_split_kernel<<<dim3(80, 48), 256, 0, stream>>>(Qb, Kb, Vt, Yb, Opart, lpart);
    attn_combine_kernel<<<dim3(24, 48), 256, 0, stream>>>(Opart, lpart, Yb);
  } else {
    attn_kernel<<<dim3(16, 48), 256, 0, stream>>>(Qb, Kb, Vt, Yb);
  }
  gemm_proj_kernel<<<dim3(6, 128), 256, 0, stream>>>(Yb, WprojT, b_proj, out);
}

// Round 9
// 232.034 us; speedup vs baseline: 3.9089x; 1.0553x over previous
//
#include <hip/hip_runtime.h>
#include <hip/hip_bf16.h>

typedef __bf16 bf16x8 __attribute__((ext_vector_type(8)));
typedef float f32x4 __attribute__((ext_vector_type(4)));
typedef unsigned int u32x4 __attribute__((ext_vector_type(4)));
typedef unsigned int u32x2 __attribute__((ext_vector_type(2)));
typedef unsigned short u16;
typedef unsigned long long u64;

__device__ __forceinline__ u16 f2bf(float f) {
  unsigned u = __builtin_bit_cast(unsigned, f);
  u += 0x7FFFu + ((u >> 16) & 1u);   // RNE
  return (u16)(u >> 16);
}
// HW packed convert: 2 fp32 -> 2 bf16 (v_cvt_pk_bf16_f32, RNE)
__device__ __forceinline__ unsigned cvtpk(float a, float b) {
  float2 f; f.x = a; f.y = b;
  __hip_bfloat162 h = __float22bfloat162_rn(f);
  unsigned u;
  __builtin_memcpy(&u, &h, 4);
  return u;
}

// async global->LDS direct copy, 16B per lane. LDS dest = wave-uniform base + lane*16.
__device__ __forceinline__ void gll16(const u16* g, u16* l) {
  __builtin_amdgcn_global_load_lds(
      (const __attribute__((address_space(1))) unsigned int*)g,
      (__attribute__((address_space(3))) unsigned int*)l, 16, 0, 0);
}

// ---------------- cast x (fp32 -> bf16), vectorized ----------------
__global__ void cast_x_kernel(const float* __restrict__ in, u16* __restrict__ out, int n4) {
  int i = blockIdx.x * blockDim.x + threadIdx.x;
  if (i >= n4) return;
  f32x4 v = *(const f32x4*)(in + (size_t)i * 4);
  u32x2 pk;
  pk[0] = cvtpk(v[0], v[1]);
  pk[1] = cvtpk(v[2], v[3]);
  *(u32x2*)(out + (size_t)i * 4) = pk;
}

// ------------- transpose + cast: W[K][N] fp32 -> WT[N][K] bf16 -------------
__global__ void transpose_cast_kernel(const float* __restrict__ W, u16* __restrict__ WT, int K, int N) {
  __shared__ float tile[32][33];
  int c0 = blockIdx.x * 32, r0 = blockIdx.y * 32;
  int tx = threadIdx.x & 31, tg = threadIdx.x >> 5;
#pragma unroll
  for (int i = 0; i < 4; ++i) {
    int r = tg + i * 8;
    tile[r][tx] = W[(size_t)(r0 + r) * N + c0 + tx];
  }
  __syncthreads();
#pragma unroll
  for (int i = 0; i < 4; ++i) {
    int r = tg + i * 8;
    WT[(size_t)(c0 + r) * K + r0 + tx] = f2bf(tile[tx][r]);
  }
}

// ---------------- QKV GEMM: [8192x768] x [768x2304], BK=64 ----------------
// K-halves in separate 128x32 LDS arrays (keeps the verified 64B-stride layout;
// a single 128-wide row would 16-way bank-conflict and gll16 forbids padding).
// Q pre-scaled by 0.125*log2(e). V written TRANSPOSED: Vt[bh][d][t].
__global__ __launch_bounds__(256, 4) void gemm_qkv_kernel(
    const u16* __restrict__ A, const u16* __restrict__ BT, const float* __restrict__ bias,
    u16* __restrict__ Qb, u16* __restrict__ Kb, u16* __restrict__ Vt) {
  constexpr int K = 768;
  __shared__ u16 Asm[2][128 * 32];
  __shared__ u16 Bsm[2][128 * 32];
  const int tid = threadIdx.x;
  const int w = tid >> 6, lane = tid & 63;
  const int l15 = lane & 15, quad = lane >> 4;
  const int srow = tid >> 2, scol = (tid & 3) * 8;
  const int m0 = blockIdx.y * 128, n0 = blockIdx.x * 128;
  const u16* Ag = A + (size_t)(m0 + srow) * K + scol;
  const u16* Bg = BT + (size_t)(n0 + srow) * K + scol;
  const int mw = (w >> 1) * 64, nw = (w & 1) * 64;
  f32x4 acc[4][4];
#pragma unroll
  for (int i = 0; i < 4; ++i)
#pragma unroll
    for (int j = 0; j < 4; ++j) acc[i][j] = {0.f, 0.f, 0.f, 0.f};
  for (int k0 = 0; k0 < K; k0 += 64) {
    __syncthreads();
#pragma unroll
    for (int h = 0; h < 2; ++h)
#pragma unroll
      for (int rb = 0; rb < 2; ++rb) {
        gll16(Ag + (size_t)rb * 64 * K + k0 + h * 32, &Asm[h][(rb * 64 + w * 16) * 32]);
        gll16(Bg + (size_t)rb * 64 * K + k0 + h * 32, &Bsm[h][(rb * 64 + w * 16) * 32]);
      }
    __syncthreads();
#pragma unroll
    for (int h = 0; h < 2; ++h) {
      bf16x8 af[4], bfj[4];
#pragma unroll
      for (int i = 0; i < 4; ++i) af[i] = *(const bf16x8*)&Asm[h][(mw + i * 16 + l15) * 32 + quad * 8];
#pragma unroll
      for (int j = 0; j < 4; ++j) bfj[j] = *(const bf16x8*)&Bsm[h][(nw + j * 16 + l15) * 32 + quad * 8];
#pragma unroll
      for (int i = 0; i < 4; ++i)
#pragma unroll
        for (int j = 0; j < 4; ++j)
          acc[i][j] = __builtin_amdgcn_mfma_f32_16x16x32_bf16(af[i], bfj[j], acc[i][j], 0, 0, 0);
    }
  }
  const int sec = blockIdx.x / 6;           // 0:Q 1:K 2:V (uniform per block; 768%128==0)
  const int nbase = n0 - sec * 768;
#pragma unroll
  for (int j = 0; j < 4; ++j) {
    const int nloc = nbase + nw + j * 16 + l15;
    const float bv = bias[sec * 768 + nloc];
    const int h = nloc >> 6, d = nloc & 63;
#pragma unroll
    for (int i = 0; i < 4; ++i) {
      const int m = m0 + mw + i * 16 + quad * 4;
      const int bb = m >> 11, trow = m & 2047;
      if (sec == 2) {
        u32x2 pk;
        pk[0] = cvtpk(acc[i][j][0] + bv, acc[i][j][1] + bv);
        pk[1] = cvtpk(acc[i][j][2] + bv, acc[i][j][3] + bv);
        *(u32x2*)(Vt + (size_t)((bb * 12 + h) * 64 + d) * 2048 + trow) = pk;
      } else {
        u16* dst = (sec == 0) ? Qb : Kb;
        const float scl = (sec == 0) ? 0.125f * 1.44269504f : 1.0f;
#pragma unroll
        for (int r = 0; r < 4; ++r)
          dst[(size_t)((bb * 12 + h) * 2048 + trow + r) * 64 + d] = f2bf((acc[i][j][r] + bv) * scl);
      }
    }
  }
}

// ---------------- proj GEMM: 64x128 tiles, BK=64, fp32 out + bias ----------------
__global__ __launch_bounds__(256, 4) void gemm_proj_kernel(
    const u16* __restrict__ A, const u16* __restrict__ BT, const float* __restrict__ bias,
    float* __restrict__ out) {
  constexpr int K = 768;
  __shared__ u16 Asm[2][64 * 32];
  __shared__ u16 Bsm[2][128 * 32];
  const int tid = threadIdx.x;
  const int w = tid >> 6, lane = tid & 63;
  const int l15 = lane & 15, quad = lane >> 4;
  const int srow = tid >> 2, scol = (tid & 3) * 8;
  const int m0 = blockIdx.y * 64, n0 = blockIdx.x * 128;
  const u16* Ag = A + (size_t)(m0 + srow) * K + scol;
  const u16* Bg = BT + (size_t)(n0 + srow) * K + scol;
  const int mw = (w >> 1) * 32, nw = (w & 1) * 64;
  f32x4 acc[2][4];
#pragma unroll
  for (int i = 0; i < 2; ++i)
#pragma unroll
    for (int j = 0; j < 4; ++j) acc[i][j] = {0.f, 0.f, 0.f, 0.f};
  for (int k0 = 0; k0 < K; k0 += 64) {
    __syncthreads();
#pragma unroll
    for (int h = 0; h < 2; ++h) {
      gll16(Ag + k0 + h * 32, &Asm[h][(w * 16) * 32]);
#pragma unroll
      for (int rb = 0; rb < 2; ++rb)
        gll16(Bg + (size_t)rb * 64 * K + k0 + h * 32, &Bsm[h][(rb * 64 + w * 16) * 32]);
    }
    __syncthreads();
#pragma unroll
    for (int h = 0; h < 2; ++h) {
      bf16x8 af[2], bfj[4];
#pragma unroll
      for (int i = 0; i < 2; ++i) af[i] = *(const bf16x8*)&Asm[h][(mw + i * 16 + l15) * 32 + quad * 8];
#pragma unroll
      for (int j = 0; j < 4; ++j) bfj[j] = *(const bf16x8*)&Bsm[h][(nw + j * 16 + l15) * 32 + quad * 8];
#pragma unroll
      for (int i = 0; i < 2; ++i)
#pragma unroll
        for (int j = 0; j < 4; ++j)
          acc[i][j] = __builtin_amdgcn_mfma_f32_16x16x32_bf16(af[i], bfj[j], acc[i][j], 0, 0, 0);
    }
  }
#pragma unroll
  for (int j = 0; j < 4; ++j) {
    const int n = n0 + nw + j * 16 + l15;
    const float bv = bias[n];
#pragma unroll
    for (int i = 0; i < 2; ++i) {
      const int m = m0 + mw + i * 16 + quad * 4;
#pragma unroll
      for (int r = 0; r < 4; ++r) out[(size_t)(m + r) * 768 + n] = acc[i][j][r] + bv;
    }
  }
}

// ---------------- split-K causal flash attention (fixed-max exp2 softmax) ----------------
// Work unit: (bh, 64-q tile qt, chunk of <=8 k-tiles). 80 slots per bh.
// slot decode: qt 0..7 -> 1 chunk; 8..15 -> 2; 16..23 -> 3; 24..31 -> 4.
// Single-chunk (qt<=7): write Yb directly. Else: write unnormalized fp32 O[q][d] + l partials.
__global__ __launch_bounds__(256) void attn_split_kernel(
    const u16* __restrict__ Qg, const u16* __restrict__ Kg, const u16* __restrict__ Vtg,
    u16* __restrict__ Yb, float* __restrict__ Opart, float* __restrict__ lpart) {
  constexpr int T = 2048, D = 64;
  constexpr int LDP = 72;
  constexpr float MBOUND = 20.0f;
  __shared__ u16 Ks[64 * LDP];      // K tile  [k][d]
  __shared__ u16 VTs[64 * LDP];     // V^T tile [d][k]
  __shared__ u16 Ps[4 * 16 * LDP];  // P per-wave [16 q][64 k]
  const int s = 79 - blockIdx.x;    // long chunks first
  const int bh = blockIdx.y;
  int qt, c;
  if (s < 8) { qt = s; c = 0; }
  else if (s < 24) { qt = 8 + ((s - 8) >> 1); c = (s - 8) & 1; }
  else if (s < 48) { int u = s - 24; int q3 = u / 3; qt = 16 + q3; c = u - 3 * q3; }
  else { int u = s - 48; qt = 24 + (u >> 2); c = u & 3; }
  const int niter = min(8, qt + 1 - 8 * c);
  const int tid = threadIdx.x;
  const int w = tid >> 6, lane = tid & 63;
  const int l15 = lane & 15, quad = lane >> 4;
  const int srow = tid >> 2, scol = (tid & 3) * 16;
  const u16* Kp = Kg + (size_t)bh * T * D;
  const u16* VTp = Vtg + (size_t)bh * D * T;
  u16* pw = &Ps[(w * 16) * LDP];

  // Q fragments (B-operand for S^T = K.Q^T): this wave's 16 q rows
  const int qq = qt * 64 + w * 16 + l15;
  const u16* qrow = Qg + ((size_t)bh * T + qq) * D;
  const bf16x8 qfa = *(const bf16x8*)(qrow + quad * 8);
  const bf16x8 qfb = *(const bf16x8*)(qrow + 32 + quad * 8);

  f32x4 o[4] = {{0,0,0,0},{0,0,0,0},{0,0,0,0},{0,0,0,0}};  // O^T: row=d, col=q=l15
  float lv = 0.f;

  // prefetch first tile of the chunk
  int ktg = c * 8;
  u32x4 kA = *(const u32x4*)(Kp + (size_t)(ktg * 64 + srow) * D + scol);
  u32x4 kB = *(const u32x4*)(Kp + (size_t)(ktg * 64 + srow) * D + scol + 8);
  u32x4 vA = *(const u32x4*)(VTp + (size_t)srow * T + ktg * 64 + scol);
  u32x4 vB = *(const u32x4*)(VTp + (size_t)srow * T + ktg * 64 + scol + 8);

  for (int j = 0; j < niter; ++j) {
    ktg = c * 8 + j;
    __syncthreads();
    *(u32x4*)&Ks[srow * LDP + scol] = kA;
    *(u32x4*)&Ks[srow * LDP + scol + 8] = kB;
    *(u32x4*)&VTs[srow * LDP + scol] = vA;
    *(u32x4*)&VTs[srow * LDP + scol + 8] = vB;
    __syncthreads();
    if (j + 1 < niter) {
      const int k1 = (ktg + 1) * 64;
      kA = *(const u32x4*)(Kp + (size_t)(k1 + srow) * D + scol);
      kB = *(const u32x4*)(Kp + (size_t)(k1 + srow) * D + scol + 8);
      vA = *(const u32x4*)(VTp + (size_t)srow * T + k1 + scol);
      vB = *(const u32x4*)(VTp + (size_t)srow * T + k1 + scol + 8);
    }
    // S^T = K.Q^T : C-layout row = k_local = 16t+quad*4+r, col = q = l15
    f32x4 sA[4] = {{0,0,0,0},{0,0,0,0},{0,0,0,0},{0,0,0,0}};
#pragma unroll
    for (int t = 0; t < 4; ++t) {
      const bf16x8 kf0 = *(const bf16x8*)&Ks[(t * 16 + l15) * LDP + quad * 8];
      const bf16x8 kf1 = *(const bf16x8*)&Ks[(t * 16 + l15) * LDP + 32 + quad * 8];
      sA[t] = __builtin_amdgcn_mfma_f32_16x16x32_bf16(kf0, qfa, sA[t], 0, 0, 0);
      sA[t] = __builtin_amdgcn_mfma_f32_16x16x32_bf16(kf1, qfb, sA[t], 0, 0, 0);
    }
    if (ktg == qt) {  // diagonal tile: causal mask
      const int k0 = ktg * 64;
#pragma unroll
      for (int t = 0; t < 4; ++t)
#pragma unroll
        for (int r = 0; r < 4; ++r)
          if (k0 + t * 16 + quad * 4 + r > qq) sA[t][r] = -1e30f;
    }
    // fixed-max softmax: p = 2^(s-M), no cross-lane ops
#pragma unroll
    for (int t = 0; t < 4; ++t) {
      float e0 = __builtin_amdgcn_exp2f(sA[t][0] - MBOUND);
      float e1 = __builtin_amdgcn_exp2f(sA[t][1] - MBOUND);
      float e2 = __builtin_amdgcn_exp2f(sA[t][2] - MBOUND);
      float e3 = __builtin_amdgcn_exp2f(sA[t][3] - MBOUND);
      lv += (e0 + e1) + (e2 + e3);
      u32x2 pk;
      pk[0] = cvtpk(e0, e1);
      pk[1] = cvtpk(e2, e3);
      *(u32x2*)&pw[l15 * LDP + t * 16 + quad * 4] = pk;
    }
    // O^T += V^T.P^T
    const bf16x8 pa = *(const bf16x8*)&pw[l15 * LDP + quad * 8];
    const bf16x8 pb = *(const bf16x8*)&pw[l15 * LDP + 32 + quad * 8];
#pragma unroll
    for (int t = 0; t < 4; ++t) {
      const bf16x8 vf0 = *(const bf16x8*)&VTs[(t * 16 + l15) * LDP + quad * 8];
      const bf16x8 vf1 = *(const bf16x8*)&VTs[(t * 16 + l15) * LDP + 32 + quad * 8];
      o[t] = __builtin_amdgcn_mfma_f32_16x16x32_bf16(vf0, pa, o[t], 0, 0, 0);
      o[t] = __builtin_amdgcn_mfma_f32_16x16x32_bf16(vf1, pb, o[t], 0, 0, 0);
    }
  }
  // reduce l across quads (all lanes get total for their q=l15)
  lv += __shfl_xor(lv, 16);
  lv += __shfl_xor(lv, 32);
  if (qt <= 7) {
    // single chunk: normalize + write Yb directly
    const float inv = 1.f / lv;
    const int bidx = bh / 12, hidx = bh % 12;
    u16* y = Yb + ((size_t)bidx * T + qq) * 768 + hidx * 64;
#pragma unroll
    for (int t = 0; t < 4; ++t) {
      u32x2 pk;
      pk[0] = cvtpk(o[t][0] * inv, o[t][1] * inv);
      pk[1] = cvtpk(o[t][2] * inv, o[t][3] * inv);
      *(u32x2*)(y + t * 16 + quad * 4) = pk;
    }
  } else {
    // write unnormalized partials: Opart[pidx][q(64)][d(64)] fp32, lpart[pidx][q]
    const size_t pidx = (size_t)bh * 80 + s;
    float* Op = Opart + pidx * 4096 + (size_t)(w * 16 + l15) * 64;
#pragma unroll
    for (int t = 0; t < 4; ++t) *(f32x4*)(Op + t * 16 + quad * 4) = o[t];
    if (quad == 0) lpart[pidx * 64 + w * 16 + l15] = lv;
  }
}

// ---------------- combine partials for qt >= 8 ----------------
__global__ __launch_bounds__(256) void attn_combine_kernel(
    const float* __restrict__ Opart, const float* __restrict__ lpart, u16* __restrict__ Yb) {
  constexpr int T = 2048;
  const int qt = 8 + blockIdx.x;
  const int bh = blockIdx.y;
  const int nch = (qt < 16) ? 2 : (qt < 24) ? 3 : 4;
  const int off = (qt < 16) ? 8 + (qt - 8) * 2 : (qt < 24) ? 24 + (qt - 16) * 3 : 48 + (qt - 24) * 4;
  const size_t base = (size_t)bh * 80 + off;
  const int tid = threadIdx.x;
  const int q = tid >> 2, db = (tid & 3) * 16;
  f32x4 o[4] = {{0,0,0,0},{0,0,0,0},{0,0,0,0},{0,0,0,0}};
  float l = 0.f;
  for (int cc = 0; cc < nch; ++cc) {
    const float* Op = Opart + (base + cc) * 4096 + (size_t)q * 64 + db;
#pragma unroll
    for (int v = 0; v < 4; ++v) o[v] += *(const f32x4*)(Op + v * 4);
    l += lpart[(base + cc) * 64 + q];
  }
  const float inv = 1.f / l;
  const int bidx = bh / 12, hidx = bh % 12;
  u16* y = Yb + ((size_t)bidx * T + qt * 64 + q) * 768 + hidx * 64 + db;
  u32x4 pk;
  pk[0] = cvtpk(o[0][0] * inv, o[0][1] * inv);
  pk[1] = cvtpk(o[0][2] * inv, o[0][3] * inv);
  pk[2] = cvtpk(o[1][0] * inv, o[1][1] * inv);
  pk[3] = cvtpk(o[1][2] * inv, o[1][3] * inv);
  *(u32x4*)y = pk;
  pk[0] = cvtpk(o[2][0] * inv, o[2][1] * inv);
  pk[1] = cvtpk(o[2][2] * inv, o[2][3] * inv);
  pk[2] = cvtpk(o[3][0] * inv, o[3][1] * inv);
  pk[3] = cvtpk(o[3][2] * inv, o[3][3] * inv);
  *(u32x4*)(y + 8) = pk;
}

// ---------------- fallback: round-7 attention (used if ws too small) ----------------
__global__ __launch_bounds__(256) void attn_kernel(
    const u16* __restrict__ Qg, const u16* __restrict__ Kg, const u16* __restrict__ Vtg,
    u16* __restrict__ Yb) {
  constexpr int T = 2048, D = 64;
  constexpr int LDP = 72;
  constexpr float MBOUND = 20.0f;
  __shared__ u16 Ks[64 * LDP];
  __shared__ u16 VTs[64 * LDP];
  __shared__ u16 Ps[4 * 32 * LDP];
  const int qb = 15 - blockIdx.x;
  const int bh = blockIdx.y;
  const int Q0 = qb * 128;
  const int bidx = bh / 12, hidx = bh % 12;
  const int tid = threadIdx.x;
  const int w = tid >> 6, lane = tid & 63;
  const int l15 = lane & 15, quad = lane >> 4;
  const int srow = tid >> 2, scol = (tid & 3) * 16;
  const u16* Kp = Kg + (size_t)bh * T * D;
  const u16* VTp = Vtg + (size_t)bh * D * T;
  u16* pw0 = &Ps[(w * 32) * LDP];
  u16* pw1 = &Ps[(w * 32 + 16) * LDP];
  const u16* qrow0 = Qg + ((size_t)bh * T + Q0 + w * 16 + l15) * D;
  const bf16x8 qf0a = *(const bf16x8*)(qrow0 + quad * 8);
  const bf16x8 qf0b = *(const bf16x8*)(qrow0 + 32 + quad * 8);
  const bf16x8 qf1a = *(const bf16x8*)(qrow0 + (size_t)64 * D + quad * 8);
  const bf16x8 qf1b = *(const bf16x8*)(qrow0 + (size_t)64 * D + 32 + quad * 8);
  const int qq0 = Q0 + w * 16 + l15, qq1 = qq0 + 64;
  f32x4 o0[4] = {{0,0,0,0},{0,0,0,0},{0,0,0,0},{0,0,0,0}};
  f32x4 o1[4] = {{0,0,0,0},{0,0,0,0},{0,0,0,0},{0,0,0,0}};
  float l0v = 0.f, l1v = 0.f;
  const int nkt = 2 * qb + 2;
  u32x4 kA = *(const u32x4*)(Kp + (size_t)srow * D + scol);
  u32x4 kB = *(const u32x4*)(Kp + (size_t)srow * D + scol + 8);
  u32x4 vA = *(const u32x4*)(VTp + (size_t)srow * T + scol);
  u32x4 vB = *(const u32x4*)(VTp + (size_t)srow * T + scol + 8);
  for (int kt = 0; kt < nkt; ++kt) {
    __syncthreads();
    *(u32x4*)&Ks[srow * LDP + scol] = kA;
    *(u32x4*)&Ks[srow * LDP + scol + 8] = kB;
    *(u32x4*)&VTs[srow * LDP + scol] = vA;
    *(u32x4*)&VTs[srow * LDP + scol + 8] = vB;
    __syncthreads();
    if (kt + 1 < nkt) {
      const int k1 = (kt + 1) * 64;
      kA = *(const u32x4*)(Kp + (size_t)(k1 + srow) * D + scol);
      kB = *(const u32x4*)(Kp + (size_t)(k1 + srow) * D + scol + 8);
      vA = *(const u32x4*)(VTp + (size_t)srow * T + k1 + scol);
      vB = *(const u32x4*)(VTp + (size_t)srow * T + k1 + scol + 8);
    }
    const int k0 = kt * 64;
    const bool g0a = (kt <= 2 * qb);
    f32x4 s0[4] = {{0,0,0,0},{0,0,0,0},{0,0,0,0},{0,0,0,0}};
    f32x4 s1[4] = {{0,0,0,0},{0,0,0,0},{0,0,0,0},{0,0,0,0}};
#pragma unroll
    for (int t = 0; t < 4; ++t) {
      const bf16x8 kf0 = *(const bf16x8*)&Ks[(t * 16 + l15) * LDP + quad * 8];
      const bf16x8 kf1 = *(const bf16x8*)&Ks[(t * 16 + l15) * LDP + 32 + quad * 8];
      s0[t] = __builtin_amdgcn_mfma_f32_16x16x32_bf16(kf0, qf0a, s0[t], 0, 0, 0);
      s0[t] = __builtin_amdgcn_mfma_f32_16x16x32_bf16(kf1, qf0b, s0[t], 0, 0, 0);
      s1[t] = __builtin_amdgcn_mfma_f32_16x16x32_bf16(kf0, qf1a, s1[t], 0, 0, 0);
      s1[t] = __builtin_amdgcn_mfma_f32_16x16x32_bf16(kf1, qf1b, s1[t], 0, 0, 0);
    }
    if (g0a) {
      if (kt == 2 * qb) {
#pragma unroll
        for (int t = 0; t < 4; ++t)
#pragma unroll
          for (int r = 0; r < 4; ++r)
            if (k0 + t * 16 + quad * 4 + r > qq0) s0[t][r] = -1e30f;
      }
#pragma unroll
      for (int t = 0; t < 4; ++t) {
        float e0 = __builtin_amdgcn_exp2f(s0[t][0] - MBOUND);
        float e1 = __builtin_amdgcn_exp2f(s0[t][1] - MBOUND);
        float e2 = __builtin_amdgcn_exp2f(s0[t][2] - MBOUND);
        float e3 = __builtin_amdgcn_exp2f(s0[t][3] - MBOUND);
        l0v += (e0 + e1) + (e2 + e3);
        u32x2 pk;
        pk[0] = cvtpk(e0, e1);
        pk[1] = cvtpk(e2, e3);
        *(u32x2*)&pw0[l15 * LDP + t * 16 + quad * 4] = pk;
      }
    }
    {
      if (kt == 2 * qb + 1) {
#pragma unroll
        for (int t = 0; t < 4; ++t)
#pragma unroll
          for (int r = 0; r < 4; ++r)
            if (k0 + t * 16 + quad * 4 + r > qq1) s1[t][r] = -1e30f;
      }
#pragma unroll
      for (int t = 0; t < 4; ++t) {
        float e0 = __builtin_amdgcn_exp2f(s1[t][0] - MBOUND);
        float e1 = __builtin_amdgcn_exp2f(s1[t][1] - MBOUND);
        float e2 = __builtin_amdgcn_exp2f(s1[t][2] - MBOUND);
        float e3 = __builtin_amdgcn_exp2f(s1[t][3] - MBOUND);
        l1v += (e0 + e1) + (e2 + e3);
        u32x2 pk;
        pk[0] = cvtpk(e0, e1);
        pk[1] = cvtpk(e2, e3);
        *(u32x2*)&pw1[l15 * LDP + t * 16 + quad * 4] = pk;
      }
    }
    const bf16x8 p0a = *(const bf16x8*)&pw0[l15 * LDP + quad * 8];
    const bf16x8 p0b = *(const bf16x8*)&pw0[l15 * LDP + 32 + quad * 8];
    const bf16x8 p1a = *(const bf16x8*)&pw1[l15 * LDP + quad * 8];
    const bf16x8 p1b = *(const bf16x8*)&pw1[l15 * LDP + 32 + quad * 8];
#pragma unroll
    for (int t = 0; t < 4; ++t) {
      const bf16x8 vf0 = *(const bf16x8*)&VTs[(t * 16 + l15) * LDP + quad * 8];
      const bf16x8 vf1 = *(const bf16x8*)&VTs[(t * 16 + l15) * LDP + 32 + quad * 8];
      if (g0a) {
        o0[t] = __builtin_amdgcn_mfma_f32_16x16x32_bf16(vf0, p0a, o0[t], 0, 0, 0);
        o0[t] = __builtin_amdgcn_mfma_f32_16x16x32_bf16(vf1, p0b, o0[t], 0, 0, 0);
      }
      o1[t] = __builtin_amdgcn_mfma_f32_16x16x32_bf16(vf0, p1a, o1[t], 0, 0, 0);
      o1[t] = __builtin_amdgcn_mfma_f32_16x16x32_bf16(vf1, p1b, o1[t], 0, 0, 0);
    }
  }
  l0v += __shfl_xor(l0v, 16); l0v += __shfl_xor(l0v, 32);
  l1v += __shfl_xor(l1v, 16); l1v += __shfl_xor(l1v, 32);
  const float inv0 = 1.f / l0v, inv1 = 1.f / l1v;
  u16* y0 = Yb + ((size_t)bidx * T + qq0) * 768 + hidx * 64;
  u16* y1 = Yb + ((size_t)bidx * T + qq1) * 768 + hidx * 64;
#pragma unroll
  for (int t = 0; t < 4; ++t) {
    u32x2 pk0, pk1;
    pk0[0] = cvtpk(o0[t][0] * inv0, o0[t][1] * inv0);
    pk0[1] = cvtpk(o0[t][2] * inv0, o0[t][3] * inv0);
    pk1[0] = cvtpk(o1[t][0] * inv1, o1[t][1] * inv1);
    pk1[1] = cvtpk(o1[t][2] * inv1, o1[t][3] * inv1);
    *(u32x2*)(y0 + t * 16 + quad * 4) = pk0;
    *(u32x2*)(y1 + t * 16 + quad * 4) = pk1;
  }
}

extern "C" void kernel_launch(void* const* d_in, const int* in_sizes, int n_in,
                              void* d_out, int out_size, void* d_ws, size_t ws_size,
                              hipStream_t stream) {
  const float* x = (const float*)d_in[0];
  const float* W_qkv = (const float*)d_in[1];
  const float* b_qkv = (const float*)d_in[2];
  const float* W_proj = (const float*)d_in[3];
  const float* b_proj = (const float*)d_in[4];
  float* out = (float*)d_out;

  constexpr size_t MC = (size_t)8192 * 768;
  u16* xb = (u16*)d_ws;
  u16* Qb = xb + MC;
  u16* Kb = Qb + MC;
  u16* Vt = Kb + MC;   // transposed V: [bh][d][t]
  u16* Yb = Vt + MC;
  u16* WqkvT = Yb + MC;
  u16* WprojT = WqkvT + (size_t)2304 * 768;
  // split-K partials (after the bf16 region)
  constexpr size_t BASE_U16 = 5 * MC + (size_t)2304 * 768 + (size_t)768 * 768;  // 33,816,576
  float* Opart = (float*)((u16*)d_ws + BASE_U16);
  float* lpart = Opart + (size_t)3840 * 4096;
  constexpr size_t NEED = BASE_U16 * 2 + ((size_t)3840 * 4096 + (size_t)3840 * 64) * 4;
  const bool use_split = (ws_size >= NEED);

  cast_x_kernel<<<6291456 / (4 * 256), 256, 0, stream>>>(x, xb, 6291456 / 4);
  transpose_cast_kernel<<<dim3(2304 / 32, 768 / 32), 256, 0, stream>>>(W_qkv, WqkvT, 768, 2304);
  transpose_cast_kernel<<<dim3(768 / 32, 768 / 32), 256, 0, stream>>>(W_proj, WprojT, 768, 768);
  gemm_qkv_kernel<<<dim3(18, 64), 256, 0, stream>>>(xb, WqkvT, b_qkv, Qb, Kb, Vt);
  if (use_split) {
    attn_split_kernel<<<dim3(80, 48), 256, 0, stream>>>(Qb, Kb, Vt, Yb, Opart, lpart);
    attn_combine_kernel<<<dim3(24, 48), 256, 0, stream>>>(Opart, lpart, Yb);
  } else {
    attn_kernel<<<dim3(16, 48), 256, 0, stream>>>(Qb, Kb, Vt, Yb);
  }
  gemm_proj_kernel<<<dim3(6, 128), 256, 0, stream>>>(Yb, WprojT, b_proj, out);
}